// Round 2
// baseline (4314.363 us; speedup 1.0000x reference)
//
#include <hip/hip_runtime.h>
#include <cstdio>
#include <cstddef>

#define F_B 8
#define F_C 256
#define F_H 128
#define F_W 128
#define F_HW 16384
#define NEGV (-1000000000.0f)

__device__ __forceinline__ float wred_max(float v) {
#pragma unroll
  for (int o = 1; o < 64; o <<= 1) v = fmaxf(v, __shfl_xor(v, o));
  return v;
}
__device__ __forceinline__ float wred_sum(float v) {
#pragma unroll
  for (int o = 1; o < 64; o <<= 1) v += __shfl_xor(v, o);
  return v;
}

// ---------------- aux: concat weights/biases ----------------
__global__ void build_aux(const float* __restrict__ Wq, const float* __restrict__ Wk,
                          const float* __restrict__ bq, const float* __restrict__ bk,
                          const float* __restrict__ q_bias, const float* __restrict__ v_bias,
                          float* __restrict__ qk_w, float* __restrict__ qk_b,
                          float* __restrict__ qkv_b) {
  int t = blockIdx.x * 256 + threadIdx.x;
  if (t < 32 * 256) {
    qk_w[t] = Wq[t];
    qk_w[32 * 256 + t] = Wk[t];
  }
  if (t < 32) {
    qk_b[t] = bq[t];
    qk_b[32 + t] = bk[t];
  }
  if (t < 256) {
    qkv_b[t] = q_bias[t];
    qkv_b[256 + t] = 0.0f;
    qkv_b[512 + t] = v_bias[t];
  }
}

// ---------------- CPB MLP table: tblS[225][8] = 16*sigmoid(mlp(coords)) -----
__device__ __forceinline__ float cpb_coord(int a) {
  float v = (float)(a - 7) * (8.0f / 7.0f);
  float lg = log2f(fabsf(v) + 1.0f) * (1.0f / 3.0f);  // /log2(8)
  return (v < 0.0f) ? -lg : lg;
}

__global__ void cpb_table(const float* __restrict__ w1, const float* __restrict__ b1,
                          const float* __restrict__ w2, float* __restrict__ tblS) {
  int e = blockIdx.x;  // 0..224
  int yi = e / 15, xi = e % 15;
  float ry = cpb_coord(yi), rx = cpb_coord(xi);
  __shared__ float hid[512];
  int t = threadIdx.x;  // 256
  for (int j = t; j < 512; j += 256) {
    float hv = w1[j * 2] * ry + w1[j * 2 + 1] * rx + b1[j];
    hid[j] = fmaxf(hv, 0.0f);
  }
  __syncthreads();
  if (t < 8) {
    float s = 0.0f;
    for (int j = 0; j < 512; j++) s += hid[j] * w2[t * 512 + j];
    tblS[e * 8 + t] = 16.0f / (1.0f + __expf(-s));
  }
}

// ---------------- transpose (B,C,HW) -> (B,HW,C) ----------------
__global__ void transpose_chw_hwc(const float* __restrict__ in, float* __restrict__ out) {
  __shared__ float tile[32][33];
  int b = blockIdx.z;
  int p0 = blockIdx.x * 32;  // pixel base
  int c0 = blockIdx.y * 32;  // channel base
  const float* src = in + (size_t)b * F_C * F_HW;
  float* dst = out + (size_t)b * F_HW * F_C;
  int tx = threadIdx.x, ty = threadIdx.y;  // 32 x 8
#pragma unroll
  for (int i = 0; i < 4; i++) {
    tile[ty + i * 8][tx] = src[(size_t)(c0 + ty + i * 8) * F_HW + p0 + tx];
  }
  __syncthreads();
#pragma unroll
  for (int i = 0; i < 4; i++) {
    dst[(size_t)(p0 + ty + i * 8) * F_C + c0 + tx] = tile[tx][ty + i * 8];
  }
}

// ---------------- fp32 GEMM: C[M,N] = A[M,K=256] @ W[N,K]^T + bias ----------
// trans_out=0: row-major MxN. trans_out=1: out[((m/HW)*N + n)*HW + (m%HW)].
__global__ __launch_bounds__(256) void gemm128(const float* __restrict__ A,
                                               const float* __restrict__ Wt,
                                               const float* __restrict__ bias,
                                               float* __restrict__ Cmat, int M, int N,
                                               int trans_out) {
  const int K = 256;
  __shared__ float As[128][17];
  __shared__ float Bs[128][17];
  int m0 = blockIdx.y * 128;
  int n0 = blockIdx.x * 128;
  int tx = threadIdx.x, ty = threadIdx.y;  // 16 x 16
  int t = ty * 16 + tx;
  int lr = t >> 4;   // 0..15
  int lk = t & 15;   // 0..15
  float acc[8][8] = {};
  for (int k0 = 0; k0 < K; k0 += 16) {
#pragma unroll
    for (int i = 0; i < 8; i++) {
      int m = lr + i * 16;
      As[m][lk] = A[(size_t)(m0 + m) * K + k0 + lk];
    }
#pragma unroll
    for (int i = 0; i < 8; i++) {
      int n = lr + i * 16;
      Bs[n][lk] = (n0 + n < N) ? Wt[(size_t)(n0 + n) * K + k0 + lk] : 0.0f;
    }
    __syncthreads();
#pragma unroll
    for (int kk = 0; kk < 16; kk++) {
      float a[8], bb[8];
#pragma unroll
      for (int i = 0; i < 8; i++) a[i] = As[ty + i * 16][kk];
#pragma unroll
      for (int j = 0; j < 8; j++) bb[j] = Bs[tx + j * 16][kk];
#pragma unroll
      for (int i = 0; i < 8; i++)
#pragma unroll
        for (int j = 0; j < 8; j++) acc[i][j] += a[i] * bb[j];
    }
    __syncthreads();
  }
#pragma unroll
  for (int i = 0; i < 8; i++) {
    int m = m0 + ty + i * 16;
#pragma unroll
    for (int j = 0; j < 8; j++) {
      int n = n0 + tx + j * 16;
      if (n < N) {
        float vo = acc[i][j] + bias[n];
        if (!trans_out) {
          Cmat[(size_t)m * N + n] = vo;
        } else {
          int b = m / F_HW;
          int p = m - b * F_HW;
          Cmat[((size_t)b * N + n) * F_HW + p] = vo;
        }
      }
    }
  }
}

// ---------------- criss-cross attention ----------------
// qk: (B*HW, 64) [q|k], vt,xt,cc: (B*HW, 256)
__global__ __launch_bounds__(256) void cc_attn(const float* __restrict__ qk,
                                               const float* __restrict__ vt,
                                               const float* __restrict__ xt,
                                               const float* __restrict__ gamma,
                                               float* __restrict__ cc) {
  int p = blockIdx.x;  // 0..HW-1
  int b = blockIdx.y;
  int h = p >> 7, w = p & 127;
  int t = threadIdx.x;
  __shared__ float qs[32];
  __shared__ float att[256];
  __shared__ float sred[4];
  size_t base = (size_t)b * F_HW;
  if (t < 32) qs[t] = qk[(base + p) * 64 + t];
  __syncthreads();
  int g = t & 127;
  size_t krow = (t < 128) ? (base + (size_t)g * F_W + w) * 64 + 32
                          : (base + (size_t)h * F_W + g) * 64 + 32;
  float lg = (t < 128 && g == h) ? NEGV : 0.0f;
#pragma unroll
  for (int c2 = 0; c2 < 32; c2++) lg += qs[c2] * qk[krow + c2];
  // block softmax over 256 values (one per thread)
  float mx = wred_max(lg);
  if ((t & 63) == 0) sred[t >> 6] = mx;
  __syncthreads();
  mx = fmaxf(fmaxf(sred[0], sred[1]), fmaxf(sred[2], sred[3]));
  float ex = __expf(lg - mx);
  float sm = wred_sum(ex);
  __syncthreads();
  if ((t & 63) == 0) sred[t >> 6] = sm;
  __syncthreads();
  sm = sred[0] + sred[1] + sred[2] + sred[3];
  att[t] = ex / sm;
  __syncthreads();
  // output: thread t = channel c
  float o = 0.0f;
#pragma unroll 4
  for (int g2 = 0; g2 < 128; g2++)
    o += att[g2] * vt[(base + (size_t)g2 * F_W + w) * 256 + t];
#pragma unroll 4
  for (int v2 = 0; v2 < 128; v2++)
    o += att[128 + v2] * vt[(base + (size_t)h * F_W + v2) * 256 + t];
  size_t row = (base + p) * 256;
  cc[row + t] = gamma[0] * o + xt[row + t];
}

// ---------------- window attention (chunked) ----------------
// qkv: chunk of (n_pix, 768) rows starting at global pixel pix_base.
// out: global (B*HW, 256), channel = head*32 + d.
__global__ __launch_bounds__(256) void win_attn(const float* __restrict__ qkv, int win0,
                                                long long pix_base,
                                                const float* __restrict__ logit_scale,
                                                const float* __restrict__ tblS,
                                                float* __restrict__ out) {
  int win = win0 + blockIdx.x;  // global window id 0..2047
  int hh = blockIdx.y;          // head
  int b = win >> 8;
  int wy = (win >> 4) & 15, wx = win & 15;
  __shared__ float qs[64][36];
  __shared__ float ks[64][36];
  __shared__ float vs[64][32];
  __shared__ float att[64][65];
  int t = threadIdx.x;
  int n = t >> 2, d0 = (t & 3) * 8;
  {
    int iy = n >> 3, ix = n & 7;
    size_t pglob = (size_t)b * F_HW + (size_t)(wy * 8 + iy) * F_W + wx * 8 + ix;
    size_t qoff = (pglob - (size_t)pix_base) * 768 + hh * 32 + d0;
#pragma unroll
    for (int i = 0; i < 8; i++) qs[n][d0 + i] = qkv[qoff + i];
#pragma unroll
    for (int i = 0; i < 8; i++) ks[n][d0 + i] = qkv[qoff + 256 + i];
#pragma unroll
    for (int i = 0; i < 8; i++) vs[n][d0 + i] = qkv[qoff + 512 + i];
  }
  __syncthreads();
  // normalize q,k rows
  if (t < 128) {
    float* rowp = (t < 64) ? qs[t] : ks[t - 64];
    float ss = 0.0f;
#pragma unroll
    for (int i = 0; i < 32; i++) ss += rowp[i] * rowp[i];
    float inv = 1.0f / fmaxf(sqrtf(ss), 1e-12f);
#pragma unroll
    for (int i = 0; i < 32; i++) rowp[i] *= inv;
  }
  __syncthreads();
  float scale = __expf(fminf(logit_scale[hh], 4.605170185988091f));  // ln(100)
  int i = t >> 2;
  int iy = i >> 3, ix = i & 7;
#pragma unroll 4
  for (int jj = 0; jj < 16; jj++) {
    int j = (t & 3) * 16 + jj;
    float s = 0.0f;
#pragma unroll
    for (int d = 0; d < 32; d++) s += qs[i][d] * ks[j][d];
    int jy = j >> 3, jx = j & 7;
    int e = (iy - jy + 7) * 15 + (ix - jx + 7);
    att[i][j] = s * scale + tblS[e * 8 + hh];
  }
  // row softmax (4 lanes per row)
  float mx = -1e30f;
#pragma unroll 4
  for (int jj = 0; jj < 16; jj++) mx = fmaxf(mx, att[i][(t & 3) * 16 + jj]);
  mx = fmaxf(mx, __shfl_xor(mx, 1));
  mx = fmaxf(mx, __shfl_xor(mx, 2));
  float sm = 0.0f;
#pragma unroll 4
  for (int jj = 0; jj < 16; jj++) {
    float e2 = __expf(att[i][(t & 3) * 16 + jj] - mx);
    att[i][(t & 3) * 16 + jj] = e2;
    sm += e2;
  }
  sm += __shfl_xor(sm, 1);
  sm += __shfl_xor(sm, 2);
  float inv = 1.0f / sm;
#pragma unroll 4
  for (int jj = 0; jj < 16; jj++) att[i][(t & 3) * 16 + jj] *= inv;
  __syncthreads();
  // output
  float o[8] = {};
  int dbase = (t & 3) * 8;
  for (int j = 0; j < 64; j++) {
    float aij = att[i][j];
#pragma unroll
    for (int dd = 0; dd < 8; dd++) o[dd] += aij * vs[j][dbase + dd];
  }
  size_t orow =
      ((size_t)b * F_HW + (size_t)(wy * 8 + iy) * F_W + wx * 8 + ix) * 256 + hh * 32 + dbase;
#pragma unroll
  for (int dd = 0; dd < 8; dd++) out[orow + dd] = o[dd];
}

// ---------------- launch ----------------
extern "C" void kernel_launch(void* const* d_in, const int* in_sizes, int n_in,
                              void* d_out, int out_size, void* d_ws, size_t ws_size,
                              hipStream_t stream) {
  const float* x = (const float*)d_in[0];
  const float* y = (const float*)d_in[1];
  const float* Wq = (const float*)d_in[2];
  const float* bq = (const float*)d_in[3];
  const float* Wk = (const float*)d_in[4];
  const float* bk = (const float*)d_in[5];
  const float* Wv = (const float*)d_in[6];
  const float* bv = (const float*)d_in[7];
  const float* gamma = (const float*)d_in[8];
  const float* qkv_w = (const float*)d_in[9];
  const float* q_bias = (const float*)d_in[10];
  const float* v_bias = (const float*)d_in[11];
  const float* logit_scale = (const float*)d_in[12];
  const float* cpb_w1 = (const float*)d_in[13];
  const float* cpb_b1 = (const float*)d_in[14];
  const float* cpb_w2 = (const float*)d_in[15];
  const float* proj_w = (const float*)d_in[16];
  const float* proj_b = (const float*)d_in[17];

  float* ws = (float*)d_ws;
  const size_t NPX = (size_t)F_B * F_HW;  // 131072
  // layout (floats):
  size_t o_xt = 0;                       // NPX*256
  size_t o_yt = o_xt + NPX * 256;        // NPX*256
  size_t o_qk = o_yt + NPX * 256;        // NPX*64
  size_t o_vt = o_qk + NPX * 64;         // NPX*256
  size_t o_aux = o_vt + NPX * 256;
  size_t o_qkw = o_aux;                  // 64*256
  size_t o_qkb = o_qkw + 64 * 256;       // 64
  size_t o_qkvb = o_qkb + 64;            // 768
  size_t o_tbl = o_qkvb + 768;           // 225*8
  size_t need = (o_tbl + 225 * 8) * sizeof(float);
  // reuse:
  size_t o_cc = o_yt;    // yt dead after v-GEMM
  size_t o_att = o_xt;   // xt dead after cc_attn
  size_t o_qkvchunk = o_qk;  // qk+vt dead after cc_attn; chunk = 32768*768 fits in NPX*320
  if (ws_size < need) {
    fprintf(stderr, "kernel_launch: ws too small: %zu < %zu\n", ws_size, need);
    return;
  }
  float* xt = ws + o_xt;
  float* yt = ws + o_yt;
  float* qkb = ws + o_qk;
  float* vt = ws + o_vt;
  float* cc = ws + o_cc;
  float* attn_out = ws + o_att;
  float* qkvchunk = ws + o_qkvchunk;
  float* qk_w = ws + o_qkw;
  float* qk_b = ws + o_qkb;
  float* qkv_b = ws + o_qkvb;
  float* tblS = ws + o_tbl;

  build_aux<<<dim3(32), dim3(256), 0, stream>>>(Wq, Wk, bq, bk, q_bias, v_bias, qk_w, qk_b,
                                                qkv_b);
  cpb_table<<<dim3(225), dim3(256), 0, stream>>>(cpb_w1, cpb_b1, cpb_w2, tblS);
  transpose_chw_hwc<<<dim3(512, 8, 8), dim3(32, 8), 0, stream>>>(x, xt);
  transpose_chw_hwc<<<dim3(512, 8, 8), dim3(32, 8), 0, stream>>>(y, yt);
  // q|k projection: (BHW x 256) @ (64 x 256)^T
  gemm128<<<dim3(1, 1024), dim3(16, 16), 0, stream>>>(xt, qk_w, qk_b, qkb, (int)NPX, 64, 0);
  // v projection: (BHW x 256) @ (256 x 256)^T
  gemm128<<<dim3(2, 1024), dim3(16, 16), 0, stream>>>(yt, Wv, bv, vt, (int)NPX, 256, 0);
  // criss-cross attention + residual (cc overwrites yt)
  cc_attn<<<dim3(16384, 8), dim3(256), 0, stream>>>(qkb, vt, xt, gamma, cc);
  // window qkv projection + attention, chunked: 4 chunks x 2 batches (32768 rows)
  for (int c = 0; c < 4; c++) {
    const float* ccA = cc + (size_t)c * 32768 * 256;
    gemm128<<<dim3(6, 256), dim3(16, 16), 0, stream>>>(ccA, qkv_w, qkv_b, qkvchunk, 32768, 768,
                                                       0);
    win_attn<<<dim3(512, 8), dim3(256), 0, stream>>>(qkvchunk, c * 512, (long long)c * 32768,
                                                     logit_scale, tblS, attn_out);
  }
  // output projection with transposed (B,C,H,W) write
  gemm128<<<dim3(2, 1024), dim3(16, 16), 0, stream>>>(attn_out, proj_w, proj_b, (float*)d_out,
                                                      (int)NPX, 256, 1);
}

// Round 3
// 3082.396 us; speedup vs baseline: 1.3997x; 1.3997x over previous
//
#include <hip/hip_runtime.h>
#include <cstdio>
#include <cstddef>

#define F_B 8
#define F_C 256
#define F_H 128
#define F_W 128
#define F_HW 16384

__device__ __forceinline__ float wred_sum(float v) {
#pragma unroll
  for (int o = 1; o < 64; o <<= 1) v += __shfl_xor(v, o);
  return v;
}

// ---------------- aux: concat weights/biases ----------------
__global__ void build_aux(const float* __restrict__ Wq, const float* __restrict__ Wk,
                          const float* __restrict__ bq, const float* __restrict__ bk,
                          const float* __restrict__ q_bias, const float* __restrict__ v_bias,
                          float* __restrict__ qk_w, float* __restrict__ qk_b,
                          float* __restrict__ qkv_b) {
  int t = blockIdx.x * 256 + threadIdx.x;
  if (t < 32 * 256) {
    qk_w[t] = Wq[t];
    qk_w[32 * 256 + t] = Wk[t];
  }
  if (t < 32) {
    qk_b[t] = bq[t];
    qk_b[32 + t] = bk[t];
  }
  if (t < 256) {
    qkv_b[t] = q_bias[t];
    qkv_b[256 + t] = 0.0f;
    qkv_b[512 + t] = v_bias[t];
  }
}

// ---------------- CPB MLP table: tblS[225][8] = 16*sigmoid(mlp(coords)) -----
__device__ __forceinline__ float cpb_coord(int a) {
  float v = (float)(a - 7) * (8.0f / 7.0f);
  float lg = log2f(fabsf(v) + 1.0f) * (1.0f / 3.0f);  // /log2(8)
  return (v < 0.0f) ? -lg : lg;
}

__global__ void cpb_table(const float* __restrict__ w1, const float* __restrict__ b1,
                          const float* __restrict__ w2, float* __restrict__ tblS) {
  int e = blockIdx.x;  // 0..224
  int yi = e / 15, xi = e % 15;
  float ry = cpb_coord(yi), rx = cpb_coord(xi);
  __shared__ float hid[512];
  int t = threadIdx.x;  // 256
  for (int j = t; j < 512; j += 256) {
    float hv = w1[j * 2] * ry + w1[j * 2 + 1] * rx + b1[j];
    hid[j] = fmaxf(hv, 0.0f);
  }
  __syncthreads();
  if (t < 8) {
    float s = 0.0f;
    for (int j = 0; j < 512; j++) s += hid[j] * w2[t * 512 + j];
    tblS[e * 8 + t] = 16.0f / (1.0f + __expf(-s));
  }
}

// ---------------- transpose (B,C,HW) -> (B,HW,C) ----------------
__global__ void transpose_chw_hwc(const float* __restrict__ in, float* __restrict__ out) {
  __shared__ float tile[32][33];
  int b = blockIdx.z;
  int p0 = blockIdx.x * 32;  // pixel base
  int c0 = blockIdx.y * 32;  // channel base
  const float* src = in + (size_t)b * F_C * F_HW;
  float* dst = out + (size_t)b * F_HW * F_C;
  int tx = threadIdx.x, ty = threadIdx.y;  // 32 x 8
#pragma unroll
  for (int i = 0; i < 4; i++) {
    tile[ty + i * 8][tx] = src[(size_t)(c0 + ty + i * 8) * F_HW + p0 + tx];
  }
  __syncthreads();
#pragma unroll
  for (int i = 0; i < 4; i++) {
    dst[(size_t)(p0 + ty + i * 8) * F_C + c0 + tx] = tile[tx][ty + i * 8];
  }
}

// ---------------- fp32 GEMM: C[M,N] = A[M,K=256] @ W[N,K]^T + bias ----------
// trans_out=0: row-major MxN. trans_out=1: out[((m/HW)*N + n)*HW + (m%HW)].
__global__ __launch_bounds__(256) void gemm128(const float* __restrict__ A,
                                               const float* __restrict__ Wt,
                                               const float* __restrict__ bias,
                                               float* __restrict__ Cmat, int M, int N,
                                               int trans_out) {
  const int K = 256;
  __shared__ float As[128][17];
  __shared__ float Bs[128][17];
  int m0 = blockIdx.y * 128;
  int n0 = blockIdx.x * 128;
  int tx = threadIdx.x, ty = threadIdx.y;  // 16 x 16
  int t = ty * 16 + tx;
  int lr = t >> 4;   // 0..15
  int lk = t & 15;   // 0..15
  float acc[8][8] = {};
  for (int k0 = 0; k0 < K; k0 += 16) {
#pragma unroll
    for (int i = 0; i < 8; i++) {
      int m = lr + i * 16;
      As[m][lk] = A[(size_t)(m0 + m) * K + k0 + lk];
    }
#pragma unroll
    for (int i = 0; i < 8; i++) {
      int n = lr + i * 16;
      Bs[n][lk] = (n0 + n < N) ? Wt[(size_t)(n0 + n) * K + k0 + lk] : 0.0f;
    }
    __syncthreads();
#pragma unroll
    for (int kk = 0; kk < 16; kk++) {
      float a[8], bb[8];
#pragma unroll
      for (int i = 0; i < 8; i++) a[i] = As[ty + i * 16][kk];
#pragma unroll
      for (int j = 0; j < 8; j++) bb[j] = Bs[tx + j * 16][kk];
#pragma unroll
      for (int i = 0; i < 8; i++)
#pragma unroll
        for (int j = 0; j < 8; j++) acc[i][j] += a[i] * bb[j];
    }
    __syncthreads();
  }
#pragma unroll
  for (int i = 0; i < 8; i++) {
    int m = m0 + ty + i * 16;
#pragma unroll
    for (int j = 0; j < 8; j++) {
      int n = n0 + tx + j * 16;
      if (n < N) {
        float vo = acc[i][j] + bias[n];
        if (!trans_out) {
          Cmat[(size_t)m * N + n] = vo;
        } else {
          int b = m / F_HW;
          int p = m - b * F_HW;
          Cmat[((size_t)b * N + n) * F_HW + p] = vo;
        }
      }
    }
  }
}

// ---------------- criss-cross logits ----------------
// MODE 0 (H/column): block (w=x, b); E[h,g] = q(h,x)·k(g,x); write e[pix(h,x)][g], diag->0
// MODE 1 (W/row):    block (h=x, b); E[w,v] = q(x,w)·k(x,v); write e[pix(x,w)][128+v]
// e holds UNNORMALIZED exp(logit). qk rows: [q(32)|k(32)].
template <int MODE>
__global__ __launch_bounds__(256) void cc_logits(const float* __restrict__ qk,
                                                 float* __restrict__ e) {
  int x = blockIdx.x;
  int b = blockIdx.y;
  size_t base = (size_t)b * F_HW;
  __shared__ float kt[32][132];  // kt[c][g]
  int t = threadIdx.x;
  {
    int gk = t >> 1, c0 = (t & 1) * 16;
    size_t krow = (MODE == 0) ? ((size_t)gk * F_W + x) : ((size_t)x * F_W + gk);
    const float4* src = (const float4*)(qk + (base + krow) * 64 + 32 + c0);
#pragma unroll
    for (int q4 = 0; q4 < 4; q4++) {
      float4 v = src[q4];
      kt[c0 + q4 * 4 + 0][gk] = v.x;
      kt[c0 + q4 * 4 + 1][gk] = v.y;
      kt[c0 + q4 * 4 + 2][gk] = v.z;
      kt[c0 + q4 * 4 + 3][gk] = v.w;
    }
  }
  __syncthreads();
  int i = t >> 1, g0 = (t & 1) * 64;
  size_t qrow = (MODE == 0) ? ((size_t)i * F_W + x) : ((size_t)x * F_W + i);
  const float4* qp = (const float4*)(qk + (base + qrow) * 64);
  float qreg[32];
#pragma unroll
  for (int q4 = 0; q4 < 8; q4++) {
    float4 v = qp[q4];
    qreg[q4 * 4 + 0] = v.x;
    qreg[q4 * 4 + 1] = v.y;
    qreg[q4 * 4 + 2] = v.z;
    qreg[q4 * 4 + 3] = v.w;
  }
  float acc[64];
#pragma unroll
  for (int g = 0; g < 64; g++) acc[g] = 0.0f;
  for (int c = 0; c < 32; c++) {
    float qv = qreg[c];
#pragma unroll
    for (int g = 0; g < 64; g++) acc[g] += qv * kt[c][g0 + g];
  }
  if (MODE == 0) {
    int d = i - g0;
    if (d >= 0 && d < 64) acc[d] = -1e9f;  // diag mask -> exp = 0
  }
  float* ep = e + (base + qrow) * 256 + MODE * 128 + g0;
#pragma unroll
  for (int g = 0; g < 64; g += 4) {
    float4 v;
    v.x = __expf(acc[g + 0]);
    v.y = __expf(acc[g + 1]);
    v.z = __expf(acc[g + 2]);
    v.w = __expf(acc[g + 3]);
    *(float4*)(ep + g) = v;
  }
}

// ---------------- per-pixel reciprocal softmax denominator ----------------
__global__ __launch_bounds__(256) void cc_sums(const float* __restrict__ e,
                                               float* __restrict__ rsum) {
  int wave = (blockIdx.x * 256 + threadIdx.x) >> 6;
  int lane = threadIdx.x & 63;
  float4 v = *(const float4*)(e + (size_t)wave * 256 + lane * 4);
  float s = wred_sum(v.x + v.y + v.z + v.w);
  if (lane == 0) rsum[wave] = 1.0f / s;
}

// ---------------- criss-cross PV: cc += gamma * (A_norm @ V) ----------------
// MODE 0: block (w=x,b): O[h,c] = sum_g A[pix(h,x)][g]     * vt[pix(g,x)][c]
// MODE 1: block (h=x,b): O[w,c] = sum_v A[pix(x,w)][128+v] * vt[pix(x,v)][c]
template <int MODE>
__global__ __launch_bounds__(256) void cc_pv(const float* __restrict__ e,
                                             const float* __restrict__ vt,
                                             const float* __restrict__ rsum,
                                             const float* __restrict__ gamma,
                                             float* __restrict__ cc) {
  int x = blockIdx.x;
  int b = blockIdx.y;
  size_t base = (size_t)b * F_HW;
  __shared__ float at[32][132];   // at[k][i] = A^T chunk (normalized)
  __shared__ float vsh[32][132];  // vsh[k][c-half]
  __shared__ float rin[128];
  int t = threadIdx.x;
  if (t < 128) {
    size_t pr = (MODE == 0) ? ((size_t)t * F_W + x) : ((size_t)x * F_W + t);
    rin[t] = rsum[base + pr];
  }
  float gm = gamma[0];
  int ty = t >> 4, tx = t & 15;
  int i_a = t >> 1, kk0_a = (t & 1) * 16;
  size_t prow_a = (MODE == 0) ? ((size_t)i_a * F_W + x) : ((size_t)x * F_W + i_a);
  int kv = t >> 3, cb = (t & 7) * 16;
#pragma unroll
  for (int pass = 0; pass < 2; pass++) {
    int c0 = pass * 128;
    float acc[8][8];
#pragma unroll
    for (int ii = 0; ii < 8; ii++)
#pragma unroll
      for (int jj = 0; jj < 8; jj++) acc[ii][jj] = 0.0f;
    for (int k0 = 0; k0 < 128; k0 += 32) {
      __syncthreads();
      {
        const float4* ep =
            (const float4*)(e + (base + prow_a) * 256 + MODE * 128 + k0 + kk0_a);
        float rv = rin[i_a];
#pragma unroll
        for (int q4 = 0; q4 < 4; q4++) {
          float4 v = ep[q4];
          at[kk0_a + q4 * 4 + 0][i_a] = v.x * rv;
          at[kk0_a + q4 * 4 + 1][i_a] = v.y * rv;
          at[kk0_a + q4 * 4 + 2][i_a] = v.z * rv;
          at[kk0_a + q4 * 4 + 3][i_a] = v.w * rv;
        }
      }
      {
        size_t vrow = (MODE == 0) ? ((size_t)(k0 + kv) * F_W + x)
                                  : ((size_t)x * F_W + (k0 + kv));
        const float4* vp = (const float4*)(vt + (base + vrow) * 256 + c0 + cb);
#pragma unroll
        for (int q4 = 0; q4 < 4; q4++) {
          float4 v = vp[q4];
          vsh[kv][cb + q4 * 4 + 0] = v.x;
          vsh[kv][cb + q4 * 4 + 1] = v.y;
          vsh[kv][cb + q4 * 4 + 2] = v.z;
          vsh[kv][cb + q4 * 4 + 3] = v.w;
        }
      }
      __syncthreads();
#pragma unroll 4
      for (int kk = 0; kk < 32; kk++) {
        float av[8], bv[8];
#pragma unroll
        for (int u = 0; u < 8; u++) av[u] = at[kk][ty * 8 + u];
#pragma unroll
        for (int u = 0; u < 8; u++) bv[u] = vsh[kk][tx * 8 + u];
#pragma unroll
        for (int ii = 0; ii < 8; ii++)
#pragma unroll
          for (int jj = 0; jj < 8; jj++) acc[ii][jj] += av[ii] * bv[jj];
      }
    }
#pragma unroll
    for (int ii = 0; ii < 8; ii++) {
      int irow = ty * 8 + ii;
      size_t pr = (MODE == 0) ? ((size_t)irow * F_W + x) : ((size_t)x * F_W + irow);
      float* cp = cc + (base + pr) * 256 + c0 + tx * 8;
      float4 o0 = *(float4*)(cp);
      float4 o1 = *(float4*)(cp + 4);
      o0.x += gm * acc[ii][0];
      o0.y += gm * acc[ii][1];
      o0.z += gm * acc[ii][2];
      o0.w += gm * acc[ii][3];
      o1.x += gm * acc[ii][4];
      o1.y += gm * acc[ii][5];
      o1.z += gm * acc[ii][6];
      o1.w += gm * acc[ii][7];
      *(float4*)(cp) = o0;
      *(float4*)(cp + 4) = o1;
    }
  }
}

// ---------------- window attention (chunked) ----------------
__global__ __launch_bounds__(256) void win_attn(const float* __restrict__ qkv, int win0,
                                                long long pix_base,
                                                const float* __restrict__ logit_scale,
                                                const float* __restrict__ tblS,
                                                float* __restrict__ out) {
  int win = win0 + blockIdx.x;  // global window id 0..2047
  int hh = blockIdx.y;          // head
  int b = win >> 8;
  int wy = (win >> 4) & 15, wx = win & 15;
  __shared__ float qs[64][36];
  __shared__ float ks[64][36];
  __shared__ float vs[64][32];
  __shared__ float att[64][65];
  int t = threadIdx.x;
  int n = t >> 2, d0 = (t & 3) * 8;
  {
    int iy = n >> 3, ix = n & 7;
    size_t pglob = (size_t)b * F_HW + (size_t)(wy * 8 + iy) * F_W + wx * 8 + ix;
    size_t qoff = (pglob - (size_t)pix_base) * 768 + hh * 32 + d0;
#pragma unroll
    for (int i = 0; i < 8; i++) qs[n][d0 + i] = qkv[qoff + i];
#pragma unroll
    for (int i = 0; i < 8; i++) ks[n][d0 + i] = qkv[qoff + 256 + i];
#pragma unroll
    for (int i = 0; i < 8; i++) vs[n][d0 + i] = qkv[qoff + 512 + i];
  }
  __syncthreads();
  if (t < 128) {
    float* rowp = (t < 64) ? qs[t] : ks[t - 64];
    float ss = 0.0f;
#pragma unroll
    for (int i = 0; i < 32; i++) ss += rowp[i] * rowp[i];
    float inv = 1.0f / fmaxf(sqrtf(ss), 1e-12f);
#pragma unroll
    for (int i = 0; i < 32; i++) rowp[i] *= inv;
  }
  __syncthreads();
  float scale = __expf(fminf(logit_scale[hh], 4.605170185988091f));  // ln(100)
  int i = t >> 2;
  int iy = i >> 3, ix = i & 7;
#pragma unroll 4
  for (int jj = 0; jj < 16; jj++) {
    int j = (t & 3) * 16 + jj;
    float s = 0.0f;
#pragma unroll
    for (int d = 0; d < 32; d++) s += qs[i][d] * ks[j][d];
    int jy = j >> 3, jx = j & 7;
    int e = (iy - jy + 7) * 15 + (ix - jx + 7);
    att[i][j] = s * scale + tblS[e * 8 + hh];
  }
  float mx = -1e30f;
#pragma unroll 4
  for (int jj = 0; jj < 16; jj++) mx = fmaxf(mx, att[i][(t & 3) * 16 + jj]);
  mx = fmaxf(mx, __shfl_xor(mx, 1));
  mx = fmaxf(mx, __shfl_xor(mx, 2));
  float sm = 0.0f;
#pragma unroll 4
  for (int jj = 0; jj < 16; jj++) {
    float e2 = __expf(att[i][(t & 3) * 16 + jj] - mx);
    att[i][(t & 3) * 16 + jj] = e2;
    sm += e2;
  }
  sm += __shfl_xor(sm, 1);
  sm += __shfl_xor(sm, 2);
  float inv = 1.0f / sm;
#pragma unroll 4
  for (int jj = 0; jj < 16; jj++) att[i][(t & 3) * 16 + jj] *= inv;
  __syncthreads();
  float o[8] = {};
  int dbase = (t & 3) * 8;
  for (int j = 0; j < 64; j++) {
    float aij = att[i][j];
#pragma unroll
    for (int dd = 0; dd < 8; dd++) o[dd] += aij * vs[j][dbase + dd];
  }
  size_t orow =
      ((size_t)b * F_HW + (size_t)(wy * 8 + iy) * F_W + wx * 8 + ix) * 256 + hh * 32 + dbase;
#pragma unroll
  for (int dd = 0; dd < 8; dd++) out[orow + dd] = o[dd];
}

// ---------------- launch ----------------
extern "C" void kernel_launch(void* const* d_in, const int* in_sizes, int n_in,
                              void* d_out, int out_size, void* d_ws, size_t ws_size,
                              hipStream_t stream) {
  const float* x = (const float*)d_in[0];
  const float* y = (const float*)d_in[1];
  const float* Wq = (const float*)d_in[2];
  const float* bq = (const float*)d_in[3];
  const float* Wk = (const float*)d_in[4];
  const float* bk = (const float*)d_in[5];
  const float* Wv = (const float*)d_in[6];
  const float* bv = (const float*)d_in[7];
  const float* gamma = (const float*)d_in[8];
  const float* qkv_w = (const float*)d_in[9];
  const float* q_bias = (const float*)d_in[10];
  const float* v_bias = (const float*)d_in[11];
  const float* logit_scale = (const float*)d_in[12];
  const float* cpb_w1 = (const float*)d_in[13];
  const float* cpb_b1 = (const float*)d_in[14];
  const float* cpb_w2 = (const float*)d_in[15];
  const float* proj_w = (const float*)d_in[16];
  const float* proj_b = (const float*)d_in[17];

  float* ws = (float*)d_ws;
  const size_t NPX = (size_t)F_B * F_HW;  // 131072
  // layout (floats):
  size_t o_cc = 0;                  // x^T, becomes cc in place, then qkv-GEMM input
  size_t o_yt = NPX * 256;          // y^T -> e (exp logits) -> attn_out
  size_t o_qk = 2 * NPX * 256;      // qk (NPX*64); later qkv chunk (25.2M < 41.9M capacity)
  size_t o_vt = o_qk + NPX * 64;    // v^T
  size_t o_aux = o_vt + NPX * 256;
  size_t o_qkw = o_aux;             // 64*256
  size_t o_qkb = o_qkw + 64 * 256;  // 64
  size_t o_qkvb = o_qkb + 64;       // 768
  size_t o_tbl = o_qkvb + 768;      // 225*8
  size_t o_rsum = o_tbl + 225 * 8;  // NPX
  size_t need = (o_rsum + NPX) * sizeof(float);
  if (ws_size < need) {
    fprintf(stderr, "kernel_launch: ws too small: %zu < %zu\n", ws_size, need);
    return;
  }
  float* cc = ws + o_cc;
  float* yt = ws + o_yt;
  float* e = ws + o_yt;
  float* attn_out = ws + o_yt;
  float* qkb = ws + o_qk;
  float* qkvchunk = ws + o_qk;
  float* vt = ws + o_vt;
  float* qk_w = ws + o_qkw;
  float* qk_b = ws + o_qkb;
  float* qkv_b = ws + o_qkvb;
  float* tblS = ws + o_tbl;
  float* rsum = ws + o_rsum;

  build_aux<<<dim3(32), dim3(256), 0, stream>>>(Wq, Wk, bq, bk, q_bias, v_bias, qk_w, qk_b,
                                                qkv_b);
  cpb_table<<<dim3(225), dim3(256), 0, stream>>>(cpb_w1, cpb_b1, cpb_w2, tblS);
  // x^T directly into cc (residual pre-init); y^T into yt
  transpose_chw_hwc<<<dim3(512, 8, 8), dim3(32, 8), 0, stream>>>(x, cc);
  transpose_chw_hwc<<<dim3(512, 8, 8), dim3(32, 8), 0, stream>>>(y, yt);
  // q|k projection: (BHW x 256) @ (64 x 256)^T
  gemm128<<<dim3(1, 1024), dim3(16, 16), 0, stream>>>(cc, qk_w, qk_b, qkb, (int)NPX, 64, 0);
  // v projection: (BHW x 256) @ (256 x 256)^T  (consumes yt)
  gemm128<<<dim3(2, 1024), dim3(16, 16), 0, stream>>>(yt, Wv, bv, vt, (int)NPX, 256, 0);
  // criss-cross attention, GEMM-structured (e overlays dead yt)
  cc_logits<0><<<dim3(128, 8), dim3(256), 0, stream>>>(qkb, e);
  cc_logits<1><<<dim3(128, 8), dim3(256), 0, stream>>>(qkb, e);
  cc_sums<<<dim3(32768), dim3(256), 0, stream>>>(e, rsum);
  cc_pv<0><<<dim3(128, 8), dim3(256), 0, stream>>>(e, vt, rsum, gamma, cc);
  cc_pv<1><<<dim3(128, 8), dim3(256), 0, stream>>>(e, vt, rsum, gamma, cc);
  // window qkv projection + attention, chunked: 4 chunks x 2 batches (32768 rows)
  for (int c = 0; c < 4; c++) {
    const float* ccA = cc + (size_t)c * 32768 * 256;
    gemm128<<<dim3(6, 256), dim3(16, 16), 0, stream>>>(ccA, qkv_w, qkv_b, qkvchunk, 32768, 768,
                                                       0);
    win_attn<<<dim3(512, 8), dim3(256), 0, stream>>>(qkvchunk, c * 512, (long long)c * 32768,
                                                     logit_scale, tblS, attn_out);
  }
  // output projection with transposed (B,C,H,W) write
  gemm128<<<dim3(2, 1024), dim3(16, 16), 0, stream>>>(attn_out, proj_w, proj_b, (float*)d_out,
                                                      (int)NPX, 256, 1);
}

// Round 4
// 1259.913 us; speedup vs baseline: 3.4243x; 2.4465x over previous
//
#include <hip/hip_runtime.h>
#include <cstdio>
#include <cstddef>
#include <cstdint>

#define F_B 8
#define F_C 256
#define F_H 128
#define F_W 128
#define F_HW 16384

typedef __attribute__((ext_vector_type(8))) short short8;   // bf16x8 MFMA operand
typedef __attribute__((ext_vector_type(4))) float float4v;  // MFMA accumulator

__device__ __forceinline__ float wred_sum(float v) {
#pragma unroll
  for (int o = 1; o < 64; o <<= 1) v += __shfl_xor(v, o);
  return v;
}

__device__ __forceinline__ unsigned short f2bf(float f) {
  union {
    float f;
    uint32_t u;
  } v;
  v.f = f;
  return (unsigned short)((v.u + 0x7fffu + ((v.u >> 16) & 1u)) >> 16);
}

__device__ __forceinline__ void async_copy16(const unsigned short* g, unsigned short* l) {
  __builtin_amdgcn_global_load_lds((const __attribute__((address_space(1))) void*)g,
                                   (__attribute__((address_space(3))) void*)l, 16, 0, 0);
}

// ---------------- aux: weight bf16 conversion + bias concat ----------------
__global__ void build_aux2(const float* __restrict__ Wq, const float* __restrict__ Wk,
                           const float* __restrict__ bq, const float* __restrict__ bk,
                           const float* __restrict__ q_bias, const float* __restrict__ v_bias,
                           const float* __restrict__ Wv, const float* __restrict__ qkv_w,
                           const float* __restrict__ proj_w, unsigned short* __restrict__ qk_wb,
                           float* __restrict__ qk_b, float* __restrict__ qkv_b,
                           unsigned short* __restrict__ Wvb, unsigned short* __restrict__ qkv_wb,
                           unsigned short* __restrict__ proj_wb) {
  int t = blockIdx.x * 256 + threadIdx.x;  // 768 blocks -> 196608 threads
  if (t < 8192) {
    qk_wb[t] = f2bf(Wq[t]);
    qk_wb[8192 + t] = f2bf(Wk[t]);
  }
  if (t < 65536) {
    Wvb[t] = f2bf(Wv[t]);
    proj_wb[t] = f2bf(proj_w[t]);
  }
  if (t < 196608) qkv_wb[t] = f2bf(qkv_w[t]);
  if (t < 32) {
    qk_b[t] = bq[t];
    qk_b[32 + t] = bk[t];
  }
  if (t < 256) {
    qkv_b[t] = q_bias[t];
    qkv_b[256 + t] = 0.0f;
    qkv_b[512 + t] = v_bias[t];
  }
}

// ---------------- CPB MLP table: tblS[225][8] = 16*sigmoid(mlp(coords)) -----
__device__ __forceinline__ float cpb_coord(int a) {
  float v = (float)(a - 7) * (8.0f / 7.0f);
  float lg = log2f(fabsf(v) + 1.0f) * (1.0f / 3.0f);  // /log2(8)
  return (v < 0.0f) ? -lg : lg;
}

__global__ void cpb_table(const float* __restrict__ w1, const float* __restrict__ b1,
                          const float* __restrict__ w2, float* __restrict__ tblS) {
  int e = blockIdx.x;  // 0..224
  int yi = e / 15, xi = e % 15;
  float ry = cpb_coord(yi), rx = cpb_coord(xi);
  __shared__ float hid[512];
  int t = threadIdx.x;  // 256
  for (int j = t; j < 512; j += 256) {
    float hv = w1[j * 2] * ry + w1[j * 2 + 1] * rx + b1[j];
    hid[j] = fmaxf(hv, 0.0f);
  }
  __syncthreads();
  if (t < 8) {
    float s = 0.0f;
    for (int j = 0; j < 512; j++) s += hid[j] * w2[t * 512 + j];
    tblS[e * 8 + t] = 16.0f / (1.0f + __expf(-s));
  }
}

// ---------------- transpose (B,C,HW) -> (B,HW,C); fp32 + bf16 dual ---------
__global__ void transpose_x(const float* __restrict__ in, float* __restrict__ outf,
                            unsigned short* __restrict__ outb) {
  __shared__ float tile[32][33];
  int b = blockIdx.z;
  int p0 = blockIdx.x * 32;
  int c0 = blockIdx.y * 32;
  const float* src = in + (size_t)b * F_C * F_HW;
  int tx = threadIdx.x, ty = threadIdx.y;  // 32 x 8
#pragma unroll
  for (int i = 0; i < 4; i++) {
    tile[ty + i * 8][tx] = src[(size_t)(c0 + ty + i * 8) * F_HW + p0 + tx];
  }
  __syncthreads();
#pragma unroll
  for (int i = 0; i < 4; i++) {
    size_t idx = (size_t)b * F_HW * F_C + (size_t)(p0 + ty + i * 8) * F_C + c0 + tx;
    float v = tile[tx][ty + i * 8];
    outf[idx] = v;
    outb[idx] = f2bf(v);
  }
}

__global__ void transpose_y(const float* __restrict__ in, unsigned short* __restrict__ outb) {
  __shared__ float tile[32][33];
  int b = blockIdx.z;
  int p0 = blockIdx.x * 32;
  int c0 = blockIdx.y * 32;
  const float* src = in + (size_t)b * F_C * F_HW;
  int tx = threadIdx.x, ty = threadIdx.y;  // 32 x 8
#pragma unroll
  for (int i = 0; i < 4; i++) {
    tile[ty + i * 8][tx] = src[(size_t)(c0 + ty + i * 8) * F_HW + p0 + tx];
  }
  __syncthreads();
#pragma unroll
  for (int i = 0; i < 4; i++) {
    size_t idx = (size_t)b * F_HW * F_C + (size_t)(p0 + ty + i * 8) * F_C + c0 + tx;
    outb[idx] = f2bf(tile[tx][ty + i * 8]);
  }
}

// ---------------- bf16 MFMA GEMM: C[M,N] = A[M,256] @ W[N,256]^T + bias ----
// 128 x BN tile, BK=32, 256 threads = 4 waves (2x2), wave tile 64 x BN/2.
// LDS linear; XOR swizzle ((row&3) on the 16B k-slot) applied on the global
// source during global_load_lds staging and again on the ds_read (rule #21).
// TRANS_OUT=1: out[((row>>14)*N + col)*16384 + (row&16383)]  (B,C,HW layout)
template <int BN, int TRANS_OUT>
__global__ __launch_bounds__(256) void gemm_mfma(const unsigned short* __restrict__ A,
                                                 const unsigned short* __restrict__ Wt,
                                                 const float* __restrict__ bias,
                                                 float* __restrict__ Cmat, int M, int N) {
  constexpr int WN = BN / 2;
  constexpr int NREP = WN / 16;
  __shared__ __align__(16) unsigned short As[128 * 32];
  __shared__ __align__(16) unsigned short Bs[BN * 32];
  int m0 = blockIdx.y * 128;
  int n0 = blockIdx.x * BN;
  int t = threadIdx.x;
  int wid = t >> 6, lane = t & 63;
  int wr = wid >> 1, wc = wid & 1;

  float4v acc[4][NREP] = {};

  for (int k0 = 0; k0 < 256; k0 += 32) {
    __syncthreads();
    // ---- stage A: wave stages rows [wid*32, wid*32+32) ----
#pragma unroll
    for (int j = 0; j < 2; j++) {
      int r = wid * 32 + j * 16 + (lane >> 2);
      int kg = (lane & 3) ^ (r & 3);  // inverse swizzle on global source
      const unsigned short* gp = A + (size_t)(m0 + r) * 256 + k0 + kg * 8;
      async_copy16(gp, As + (wid * 32 + j * 16) * 32);
    }
    // ---- stage B: wave stages rows [wid*(BN/4), +BN/4) ----
#pragma unroll
    for (int j = 0; j < BN / 64; j++) {
      int r = wid * (BN / 4) + j * 16 + (lane >> 2);
      int kg = (lane & 3) ^ (r & 3);
      const unsigned short* gp = Wt + (size_t)(n0 + r) * 256 + k0 + kg * 8;
      async_copy16(gp, Bs + (wid * (BN / 4) + j * 16) * 32);
    }
    __syncthreads();
    // ---- fragments (swizzled ds_read_b128) + MFMA ----
    short8 af[4];
#pragma unroll
    for (int mi = 0; mi < 4; mi++) {
      int row = wr * 64 + mi * 16 + (lane & 15);
      int kg = (lane >> 4) ^ (row & 3);
      af[mi] = *(const short8*)(As + row * 32 + kg * 8);
    }
    short8 bfr[NREP];
#pragma unroll
    for (int ni = 0; ni < NREP; ni++) {
      int col = wc * WN + ni * 16 + (lane & 15);
      int kg = (lane >> 4) ^ (col & 3);
      bfr[ni] = *(const short8*)(Bs + col * 32 + kg * 8);
    }
#pragma unroll
    for (int mi = 0; mi < 4; mi++)
#pragma unroll
      for (int ni = 0; ni < NREP; ni++)
        acc[mi][ni] =
            __builtin_amdgcn_mfma_f32_16x16x32_bf16(af[mi], bfr[ni], acc[mi][ni], 0, 0, 0);
  }
  // ---- epilogue: C/D layout col=lane&15, row=(lane>>4)*4+reg ----
#pragma unroll
  for (int ni = 0; ni < NREP; ni++) {
    int col = n0 + wc * WN + ni * 16 + (lane & 15);
    float bn = bias[col];
#pragma unroll
    for (int mi = 0; mi < 4; mi++) {
      int row0 = m0 + wr * 64 + mi * 16 + (lane >> 4) * 4;
#pragma unroll
      for (int r = 0; r < 4; r++) {
        float v = acc[mi][ni][r] + bn;
        int row = row0 + r;
        if (TRANS_OUT == 0) {
          Cmat[(size_t)row * N + col] = v;
        } else {
          int bb = row >> 14, p = row & 16383;
          Cmat[((size_t)bb * N + col) * F_HW + p] = v;
        }
      }
    }
  }
}

// ---------------- criss-cross logits ----------------
// MODE 0 (H/column): block (w=x, b); E[h,g] = q(h,x)·k(g,x); write e[pix(h,x)][g], diag->0
// MODE 1 (W/row):    block (h=x, b); E[w,v] = q(x,w)·k(x,v); write e[pix(x,w)][128+v]
// e holds UNNORMALIZED exp(logit). qk rows: [q(32)|k(32)].
template <int MODE>
__global__ __launch_bounds__(256) void cc_logits(const float* __restrict__ qk,
                                                 float* __restrict__ e) {
  int x = blockIdx.x;
  int b = blockIdx.y;
  size_t base = (size_t)b * F_HW;
  __shared__ float kt[32][132];  // kt[c][g]
  int t = threadIdx.x;
  {
    int gk = t >> 1, c0 = (t & 1) * 16;
    size_t krow = (MODE == 0) ? ((size_t)gk * F_W + x) : ((size_t)x * F_W + gk);
    const float4* src = (const float4*)(qk + (base + krow) * 64 + 32 + c0);
#pragma unroll
    for (int q4 = 0; q4 < 4; q4++) {
      float4 v = src[q4];
      kt[c0 + q4 * 4 + 0][gk] = v.x;
      kt[c0 + q4 * 4 + 1][gk] = v.y;
      kt[c0 + q4 * 4 + 2][gk] = v.z;
      kt[c0 + q4 * 4 + 3][gk] = v.w;
    }
  }
  __syncthreads();
  int i = t >> 1, g0 = (t & 1) * 64;
  size_t qrow = (MODE == 0) ? ((size_t)i * F_W + x) : ((size_t)x * F_W + i);
  const float4* qp = (const float4*)(qk + (base + qrow) * 64);
  float qreg[32];
#pragma unroll
  for (int q4 = 0; q4 < 8; q4++) {
    float4 v = qp[q4];
    qreg[q4 * 4 + 0] = v.x;
    qreg[q4 * 4 + 1] = v.y;
    qreg[q4 * 4 + 2] = v.z;
    qreg[q4 * 4 + 3] = v.w;
  }
  float acc[64];
#pragma unroll
  for (int g = 0; g < 64; g++) acc[g] = 0.0f;
  for (int c = 0; c < 32; c++) {
    float qv = qreg[c];
#pragma unroll
    for (int g = 0; g < 64; g++) acc[g] += qv * kt[c][g0 + g];
  }
  if (MODE == 0) {
    int d = i - g0;
    if (d >= 0 && d < 64) acc[d] = -1e9f;  // diag mask -> exp = 0
  }
  float* ep = e + (base + qrow) * 256 + MODE * 128 + g0;
#pragma unroll
  for (int g = 0; g < 64; g += 4) {
    float4 v;
    v.x = __expf(acc[g + 0]);
    v.y = __expf(acc[g + 1]);
    v.z = __expf(acc[g + 2]);
    v.w = __expf(acc[g + 3]);
    *(float4*)(ep + g) = v;
  }
}

// ---------------- per-pixel reciprocal softmax denominator ----------------
__global__ __launch_bounds__(256) void cc_sums(const float* __restrict__ e,
                                               float* __restrict__ rsum) {
  int wave = (blockIdx.x * 256 + threadIdx.x) >> 6;
  int lane = threadIdx.x & 63;
  float4 v = *(const float4*)(e + (size_t)wave * 256 + lane * 4);
  float s = wred_sum(v.x + v.y + v.z + v.w);
  if (lane == 0) rsum[wave] = 1.0f / s;
}

// ---------------- criss-cross PV: cc += gamma * (A_norm @ V) ----------------
// MODE 0: block (w=x,b): O[h,c] = sum_g A[pix(h,x)][g]     * vt[pix(g,x)][c]
// MODE 1: block (h=x,b): O[w,c] = sum_v A[pix(x,w)][128+v] * vt[pix(x,v)][c]
// MODE 1 additionally writes bf16 copy of final cc into ccb.
template <int MODE>
__global__ __launch_bounds__(256) void cc_pv(const float* __restrict__ e,
                                             const float* __restrict__ vt,
                                             const float* __restrict__ rsum,
                                             const float* __restrict__ gamma,
                                             float* __restrict__ cc,
                                             unsigned short* __restrict__ ccb) {
  int x = blockIdx.x;
  int b = blockIdx.y;
  size_t base = (size_t)b * F_HW;
  __shared__ float at[32][132];   // at[k][i] = A^T chunk (normalized)
  __shared__ float vsh[32][132];  // vsh[k][c-half]
  __shared__ float rin[128];
  int t = threadIdx.x;
  if (t < 128) {
    size_t pr = (MODE == 0) ? ((size_t)t * F_W + x) : ((size_t)x * F_W + t);
    rin[t] = rsum[base + pr];
  }
  float gm = gamma[0];
  int ty = t >> 4, tx = t & 15;
  int i_a = t >> 1, kk0_a = (t & 1) * 16;
  size_t prow_a = (MODE == 0) ? ((size_t)i_a * F_W + x) : ((size_t)x * F_W + i_a);
  int kv = t >> 3, cb = (t & 7) * 16;
#pragma unroll
  for (int pass = 0; pass < 2; pass++) {
    int c0 = pass * 128;
    float acc[8][8];
#pragma unroll
    for (int ii = 0; ii < 8; ii++)
#pragma unroll
      for (int jj = 0; jj < 8; jj++) acc[ii][jj] = 0.0f;
    for (int k0 = 0; k0 < 128; k0 += 32) {
      __syncthreads();
      {
        const float4* ep =
            (const float4*)(e + (base + prow_a) * 256 + MODE * 128 + k0 + kk0_a);
        float rv = rin[i_a];
#pragma unroll
        for (int q4 = 0; q4 < 4; q4++) {
          float4 v = ep[q4];
          at[kk0_a + q4 * 4 + 0][i_a] = v.x * rv;
          at[kk0_a + q4 * 4 + 1][i_a] = v.y * rv;
          at[kk0_a + q4 * 4 + 2][i_a] = v.z * rv;
          at[kk0_a + q4 * 4 + 3][i_a] = v.w * rv;
        }
      }
      {
        size_t vrow = (MODE == 0) ? ((size_t)(k0 + kv) * F_W + x)
                                  : ((size_t)x * F_W + (k0 + kv));
        const float4* vp = (const float4*)(vt + (base + vrow) * 256 + c0 + cb);
#pragma unroll
        for (int q4 = 0; q4 < 4; q4++) {
          float4 v = vp[q4];
          vsh[kv][cb + q4 * 4 + 0] = v.x;
          vsh[kv][cb + q4 * 4 + 1] = v.y;
          vsh[kv][cb + q4 * 4 + 2] = v.z;
          vsh[kv][cb + q4 * 4 + 3] = v.w;
        }
      }
      __syncthreads();
#pragma unroll 4
      for (int kk = 0; kk < 32; kk++) {
        float av[8], bv[8];
#pragma unroll
        for (int u = 0; u < 8; u++) av[u] = at[kk][ty * 8 + u];
#pragma unroll
        for (int u = 0; u < 8; u++) bv[u] = vsh[kk][tx * 8 + u];
#pragma unroll
        for (int ii = 0; ii < 8; ii++)
#pragma unroll
          for (int jj = 0; jj < 8; jj++) acc[ii][jj] += av[ii] * bv[jj];
      }
    }
#pragma unroll
    for (int ii = 0; ii < 8; ii++) {
      int irow = ty * 8 + ii;
      size_t pr = (MODE == 0) ? ((size_t)irow * F_W + x) : ((size_t)x * F_W + irow);
      float* cp = cc + (base + pr) * 256 + c0 + tx * 8;
      float4 o0 = *(float4*)(cp);
      float4 o1 = *(float4*)(cp + 4);
      o0.x += gm * acc[ii][0];
      o0.y += gm * acc[ii][1];
      o0.z += gm * acc[ii][2];
      o0.w += gm * acc[ii][3];
      o1.x += gm * acc[ii][4];
      o1.y += gm * acc[ii][5];
      o1.z += gm * acc[ii][6];
      o1.w += gm * acc[ii][7];
      *(float4*)(cp) = o0;
      *(float4*)(cp + 4) = o1;
      if (MODE == 1) {
        short8 pk;
        pk[0] = (short)f2bf(o0.x);
        pk[1] = (short)f2bf(o0.y);
        pk[2] = (short)f2bf(o0.z);
        pk[3] = (short)f2bf(o0.w);
        pk[4] = (short)f2bf(o1.x);
        pk[5] = (short)f2bf(o1.y);
        pk[6] = (short)f2bf(o1.z);
        pk[7] = (short)f2bf(o1.w);
        *(short8*)(ccb + (base + pr) * 256 + c0 + tx * 8) = pk;
      }
    }
  }
}

// ---------------- window attention (chunked), bf16 output ----------------
__global__ __launch_bounds__(256) void win_attn(const float* __restrict__ qkv, int win0,
                                                long long pix_base,
                                                const float* __restrict__ logit_scale,
                                                const float* __restrict__ tblS,
                                                unsigned short* __restrict__ out) {
  int win = win0 + blockIdx.x;  // global window id 0..2047
  int hh = blockIdx.y;          // head
  int b = win >> 8;
  int wy = (win >> 4) & 15, wx = win & 15;
  __shared__ float qs[64][36];
  __shared__ float ks[64][36];
  __shared__ float vs[64][32];
  __shared__ float att[64][65];
  int t = threadIdx.x;
  int n = t >> 2, d0 = (t & 3) * 8;
  {
    int iy = n >> 3, ix = n & 7;
    size_t pglob = (size_t)b * F_HW + (size_t)(wy * 8 + iy) * F_W + wx * 8 + ix;
    size_t qoff = (pglob - (size_t)pix_base) * 768 + hh * 32 + d0;
#pragma unroll
    for (int i = 0; i < 8; i++) qs[n][d0 + i] = qkv[qoff + i];
#pragma unroll
    for (int i = 0; i < 8; i++) ks[n][d0 + i] = qkv[qoff + 256 + i];
#pragma unroll
    for (int i = 0; i < 8; i++) vs[n][d0 + i] = qkv[qoff + 512 + i];
  }
  __syncthreads();
  if (t < 128) {
    float* rowp = (t < 64) ? qs[t] : ks[t - 64];
    float ss = 0.0f;
#pragma unroll
    for (int i = 0; i < 32; i++) ss += rowp[i] * rowp[i];
    float inv = 1.0f / fmaxf(sqrtf(ss), 1e-12f);
#pragma unroll
    for (int i = 0; i < 32; i++) rowp[i] *= inv;
  }
  __syncthreads();
  float scale = __expf(fminf(logit_scale[hh], 4.605170185988091f));  // ln(100)
  int i = t >> 2;
  int iy = i >> 3, ix = i & 7;
#pragma unroll 4
  for (int jj = 0; jj < 16; jj++) {
    int j = (t & 3) * 16 + jj;
    float s = 0.0f;
#pragma unroll
    for (int d = 0; d < 32; d++) s += qs[i][d] * ks[j][d];
    int jy = j >> 3, jx = j & 7;
    int e = (iy - jy + 7) * 15 + (ix - jx + 7);
    att[i][j] = s * scale + tblS[e * 8 + hh];
  }
  float mx = -1e30f;
#pragma unroll 4
  for (int jj = 0; jj < 16; jj++) mx = fmaxf(mx, att[i][(t & 3) * 16 + jj]);
  mx = fmaxf(mx, __shfl_xor(mx, 1));
  mx = fmaxf(mx, __shfl_xor(mx, 2));
  float sm = 0.0f;
#pragma unroll 4
  for (int jj = 0; jj < 16; jj++) {
    float e2 = __expf(att[i][(t & 3) * 16 + jj] - mx);
    att[i][(t & 3) * 16 + jj] = e2;
    sm += e2;
  }
  sm += __shfl_xor(sm, 1);
  sm += __shfl_xor(sm, 2);
  float inv = 1.0f / sm;
#pragma unroll 4
  for (int jj = 0; jj < 16; jj++) att[i][(t & 3) * 16 + jj] *= inv;
  __syncthreads();
  float o[8] = {};
  int dbase = (t & 3) * 8;
  for (int j = 0; j < 64; j++) {
    float aij = att[i][j];
#pragma unroll
    for (int dd = 0; dd < 8; dd++) o[dd] += aij * vs[j][dbase + dd];
  }
  size_t orow =
      ((size_t)b * F_HW + (size_t)(wy * 8 + iy) * F_W + wx * 8 + ix) * 256 + hh * 32 + dbase;
  short8 pk;
#pragma unroll
  for (int dd = 0; dd < 8; dd++) pk[dd] = (short)f2bf(o[dd]);
  *(short8*)(out + orow) = pk;
}

// ---------------- launch ----------------
extern "C" void kernel_launch(void* const* d_in, const int* in_sizes, int n_in,
                              void* d_out, int out_size, void* d_ws, size_t ws_size,
                              hipStream_t stream) {
  const float* x = (const float*)d_in[0];
  const float* y = (const float*)d_in[1];
  const float* Wq = (const float*)d_in[2];
  const float* bq = (const float*)d_in[3];
  const float* Wk = (const float*)d_in[4];
  const float* bk = (const float*)d_in[5];
  const float* Wv = (const float*)d_in[6];
  const float* bv = (const float*)d_in[7];
  const float* gamma = (const float*)d_in[8];
  const float* qkv_w = (const float*)d_in[9];
  const float* q_bias = (const float*)d_in[10];
  const float* v_bias = (const float*)d_in[11];
  const float* logit_scale = (const float*)d_in[12];
  const float* cpb_w1 = (const float*)d_in[13];
  const float* cpb_b1 = (const float*)d_in[14];
  const float* cpb_w2 = (const float*)d_in[15];
  const float* proj_w = (const float*)d_in[16];
  const float* proj_b = (const float*)d_in[17];

  float* ws = (float*)d_ws;
  const size_t NPX = (size_t)F_B * F_HW;  // 131072
  const size_t SZ = NPX * 256;            // 33.55M floats
  // regions (float offsets):
  size_t f_cc = 0;            // cc fp32 (x^T residual base, then cc)
  size_t f_e = SZ;            // e fp32; earlier: xb bf16 [0,SZ/2); later: qkvchunk fp32
  size_t f_vt = 2 * SZ;       // vt fp32; later: attn_b bf16
  size_t f_ccb = 3 * SZ;      // ccb bf16 (SZ ushorts = SZ/2 floats); earlier: ytb bf16
  size_t f_qkb = 3 * SZ + SZ / 2;  // qkb fp32 (NPX*64)
  size_t f_wb = f_qkb + NPX * 64;
  size_t o_qkwb = f_wb;              // 16384 ushort -> 8192 f
  size_t o_Wvb = o_qkwb + 8192;      // 65536 ushort -> 32768 f
  size_t o_qkvwb = o_Wvb + 32768;    // 196608 ushort -> 98304 f
  size_t o_projwb = o_qkvwb + 98304; // 65536 ushort -> 32768 f
  size_t o_qkb2 = o_projwb + 32768;  // qk_b 64 f
  size_t o_qkvb2 = o_qkb2 + 64;      // qkv_b 768 f
  size_t o_tbl = o_qkvb2 + 768;      // 1800 f
  size_t o_rsum = o_tbl + 1800;      // NPX f
  size_t need = (o_rsum + NPX) * sizeof(float);
  if (ws_size < need) {
    fprintf(stderr, "kernel_launch: ws too small: %zu < %zu\n", ws_size, need);
    return;
  }
  float* cc = ws + f_cc;
  float* e = ws + f_e;
  unsigned short* xb = (unsigned short*)(ws + f_e);
  float* qkvchunk = ws + f_e;
  float* vt = ws + f_vt;
  unsigned short* attn_b = (unsigned short*)(ws + f_vt);
  unsigned short* ccb = (unsigned short*)(ws + f_ccb);
  unsigned short* ytb = (unsigned short*)(ws + f_ccb);
  float* qkb = ws + f_qkb;
  unsigned short* qk_wb = (unsigned short*)(ws + o_qkwb);
  unsigned short* Wvb = (unsigned short*)(ws + o_Wvb);
  unsigned short* qkv_wb = (unsigned short*)(ws + o_qkvwb);
  unsigned short* proj_wb = (unsigned short*)(ws + o_projwb);
  float* qk_b = ws + o_qkb2;
  float* qkv_b = ws + o_qkvb2;
  float* tblS = ws + o_tbl;
  float* rsum = ws + o_rsum;

  build_aux2<<<dim3(768), dim3(256), 0, stream>>>(Wq, Wk, bq, bk, q_bias, v_bias, Wv, qkv_w,
                                                  proj_w, qk_wb, qk_b, qkv_b, Wvb, qkv_wb,
                                                  proj_wb);
  cpb_table<<<dim3(225), dim3(256), 0, stream>>>(cpb_w1, cpb_b1, cpb_w2, tblS);
  // x^T -> cc fp32 + xb bf16 ; y^T -> ytb bf16
  transpose_x<<<dim3(512, 8, 8), dim3(32, 8), 0, stream>>>(x, cc, xb);
  transpose_y<<<dim3(512, 8, 8), dim3(32, 8), 0, stream>>>(y, ytb);
  // q|k projection: (BHW x 256) @ (64 x 256)^T  [bf16 MFMA]
  gemm_mfma<64, 0><<<dim3(1, 1024), dim3(256), 0, stream>>>(xb, qk_wb, qk_b, qkb, (int)NPX, 64);
  // v projection: (BHW x 256) @ (256 x 256)^T  [bf16 MFMA]
  gemm_mfma<128, 0><<<dim3(2, 1024), dim3(256), 0, stream>>>(ytb, Wvb, bv, vt, (int)NPX, 256);
  // criss-cross attention (GEMM-structured)
  cc_logits<0><<<dim3(128, 8), dim3(256), 0, stream>>>(qkb, e);
  cc_logits<1><<<dim3(128, 8), dim3(256), 0, stream>>>(qkb, e);
  cc_sums<<<dim3(32768), dim3(256), 0, stream>>>(e, rsum);
  cc_pv<0><<<dim3(128, 8), dim3(256), 0, stream>>>(e, vt, rsum, gamma, cc, nullptr);
  cc_pv<1><<<dim3(128, 8), dim3(256), 0, stream>>>(e, vt, rsum, gamma, cc, ccb);
  // window qkv projection + attention, chunked: 4 chunks x 2 batches (32768 rows)
  for (int c = 0; c < 4; c++) {
    const unsigned short* ccA = ccb + (size_t)c * 32768 * 256;
    gemm_mfma<128, 0><<<dim3(6, 256), dim3(256), 0, stream>>>(ccA, qkv_wb, qkv_b, qkvchunk,
                                                              32768, 768);
    win_attn<<<dim3(512, 8), dim3(256), 0, stream>>>(qkvchunk, c * 512, (long long)c * 32768,
                                                     logit_scale, tblS, attn_b);
  }
  // output projection with transposed (B,C,H,W) write  [bf16 MFMA]
  gemm_mfma<128, 1><<<dim3(2, 1024), dim3(256), 0, stream>>>(attn_b, proj_wb, proj_b,
                                                             (float*)d_out, (int)NPX, 256);
}

// Round 5
// 1016.836 us; speedup vs baseline: 4.2429x; 1.2391x over previous
//
#include <hip/hip_runtime.h>
#include <cstdio>
#include <cstddef>
#include <cstdint>

#define F_B 8
#define F_C 256
#define F_H 128
#define F_W 128
#define F_HW 16384

typedef __attribute__((ext_vector_type(8))) short short8;   // bf16x8 MFMA operand
typedef __attribute__((ext_vector_type(4))) short short4v;  // bf16x4
typedef __attribute__((ext_vector_type(4))) float float4v;  // MFMA accumulator

__device__ __forceinline__ float wred_sum(float v) {
#pragma unroll
  for (int o = 1; o < 64; o <<= 1) v += __shfl_xor(v, o);
  return v;
}

__device__ __forceinline__ unsigned short f2bf(float f) {
  union {
    float f;
    uint32_t u;
  } v;
  v.f = f;
  return (unsigned short)((v.u + 0x7fffu + ((v.u >> 16) & 1u)) >> 16);
}

__device__ __forceinline__ float bf2f(unsigned short u) {
  union {
    uint32_t u;
    float f;
  } v;
  v.u = ((uint32_t)u) << 16;
  return v.f;
}

__device__ __forceinline__ void async_copy16(const unsigned short* g, unsigned short* l) {
  __builtin_amdgcn_global_load_lds((const __attribute__((address_space(1))) void*)g,
                                   (__attribute__((address_space(3))) void*)l, 16, 0, 0);
}

// ---------------- aux: weight bf16 conversion + bias concat ----------------
__global__ void build_aux2(const float* __restrict__ Wq, const float* __restrict__ Wk,
                           const float* __restrict__ bq, const float* __restrict__ bk,
                           const float* __restrict__ q_bias, const float* __restrict__ v_bias,
                           const float* __restrict__ Wv, const float* __restrict__ qkv_w,
                           const float* __restrict__ proj_w, unsigned short* __restrict__ qk_wb,
                           float* __restrict__ qk_b, float* __restrict__ qkv_b,
                           unsigned short* __restrict__ Wvb, unsigned short* __restrict__ qkv_wb,
                           unsigned short* __restrict__ proj_wb) {
  int t = blockIdx.x * 256 + threadIdx.x;  // 768 blocks -> 196608 threads
  if (t < 8192) {
    qk_wb[t] = f2bf(Wq[t]);
    qk_wb[8192 + t] = f2bf(Wk[t]);
  }
  if (t < 65536) {
    Wvb[t] = f2bf(Wv[t]);
    proj_wb[t] = f2bf(proj_w[t]);
  }
  if (t < 196608) qkv_wb[t] = f2bf(qkv_w[t]);
  if (t < 32) {
    qk_b[t] = bq[t];
    qk_b[32 + t] = bk[t];
  }
  if (t < 256) {
    qkv_b[t] = q_bias[t];
    qkv_b[256 + t] = 0.0f;
    qkv_b[512 + t] = v_bias[t];
  }
}

// ---------------- CPB MLP table: tblS[225][8] = 16*sigmoid(mlp(coords)) -----
__device__ __forceinline__ float cpb_coord(int a) {
  float v = (float)(a - 7) * (8.0f / 7.0f);
  float lg = log2f(fabsf(v) + 1.0f) * (1.0f / 3.0f);  // /log2(8)
  return (v < 0.0f) ? -lg : lg;
}

__global__ void cpb_table(const float* __restrict__ w1, const float* __restrict__ b1,
                          const float* __restrict__ w2, float* __restrict__ tblS) {
  int e = blockIdx.x;  // 0..224
  int yi = e / 15, xi = e % 15;
  float ry = cpb_coord(yi), rx = cpb_coord(xi);
  __shared__ float hid[512];
  int t = threadIdx.x;  // 256
  for (int j = t; j < 512; j += 256) {
    float hv = w1[j * 2] * ry + w1[j * 2 + 1] * rx + b1[j];
    hid[j] = fmaxf(hv, 0.0f);
  }
  __syncthreads();
  if (t < 8) {
    float s = 0.0f;
    for (int j = 0; j < 512; j++) s += hid[j] * w2[t * 512 + j];
    tblS[e * 8 + t] = 16.0f / (1.0f + __expf(-s));
  }
}

// ---------------- transpose (B,C,HW) -> (B,HW,C); fp32 + bf16 dual ---------
__global__ void transpose_x(const float* __restrict__ in, float* __restrict__ outf,
                            unsigned short* __restrict__ outb) {
  __shared__ float tile[32][33];
  int b = blockIdx.z;
  int p0 = blockIdx.x * 32;
  int c0 = blockIdx.y * 32;
  const float* src = in + (size_t)b * F_C * F_HW;
  int tx = threadIdx.x, ty = threadIdx.y;  // 32 x 8
#pragma unroll
  for (int i = 0; i < 4; i++) {
    tile[ty + i * 8][tx] = src[(size_t)(c0 + ty + i * 8) * F_HW + p0 + tx];
  }
  __syncthreads();
#pragma unroll
  for (int i = 0; i < 4; i++) {
    size_t idx = (size_t)b * F_HW * F_C + (size_t)(p0 + ty + i * 8) * F_C + c0 + tx;
    float v = tile[tx][ty + i * 8];
    outf[idx] = v;
    outb[idx] = f2bf(v);
  }
}

__global__ void transpose_y(const float* __restrict__ in, unsigned short* __restrict__ outb) {
  __shared__ float tile[32][33];
  int b = blockIdx.z;
  int p0 = blockIdx.x * 32;
  int c0 = blockIdx.y * 32;
  const float* src = in + (size_t)b * F_C * F_HW;
  int tx = threadIdx.x, ty = threadIdx.y;  // 32 x 8
#pragma unroll
  for (int i = 0; i < 4; i++) {
    tile[ty + i * 8][tx] = src[(size_t)(c0 + ty + i * 8) * F_HW + p0 + tx];
  }
  __syncthreads();
#pragma unroll
  for (int i = 0; i < 4; i++) {
    size_t idx = (size_t)b * F_HW * F_C + (size_t)(p0 + ty + i * 8) * F_C + c0 + tx;
    outb[idx] = f2bf(tile[tx][ty + i * 8]);
  }
}

// ---------------- bf16 MFMA GEMM: C[M,N] = A[M,256] @ W[N,256]^T + bias ----
// OUT 0: fp32 row-major. OUT 1: fp32 out[((row>>14)*N+col)*16384+(row&16383)].
// OUT 2: bf16 row-major.
template <int BN, int OUT>
__global__ __launch_bounds__(256) void gemm_mfma(const unsigned short* __restrict__ A,
                                                 const unsigned short* __restrict__ Wt,
                                                 const float* __restrict__ bias, void* Cmat,
                                                 int M, int N) {
  constexpr int WN = BN / 2;
  constexpr int NREP = WN / 16;
  __shared__ __align__(16) unsigned short As[128 * 32];
  __shared__ __align__(16) unsigned short Bs[BN * 32];
  int m0 = blockIdx.y * 128;
  int n0 = blockIdx.x * BN;
  int t = threadIdx.x;
  int wid = t >> 6, lane = t & 63;
  int wr = wid >> 1, wc = wid & 1;

  float4v acc[4][NREP] = {};

  for (int k0 = 0; k0 < 256; k0 += 32) {
    __syncthreads();
#pragma unroll
    for (int j = 0; j < 2; j++) {
      int r = wid * 32 + j * 16 + (lane >> 2);
      int kg = (lane & 3) ^ (r & 3);  // inverse swizzle on global source
      const unsigned short* gp = A + (size_t)(m0 + r) * 256 + k0 + kg * 8;
      async_copy16(gp, As + (wid * 32 + j * 16) * 32);
    }
#pragma unroll
    for (int j = 0; j < BN / 64; j++) {
      int r = wid * (BN / 4) + j * 16 + (lane >> 2);
      int kg = (lane & 3) ^ (r & 3);
      const unsigned short* gp = Wt + (size_t)(n0 + r) * 256 + k0 + kg * 8;
      async_copy16(gp, Bs + (wid * (BN / 4) + j * 16) * 32);
    }
    __syncthreads();
    short8 af[4];
#pragma unroll
    for (int mi = 0; mi < 4; mi++) {
      int row = wr * 64 + mi * 16 + (lane & 15);
      int kg = (lane >> 4) ^ (row & 3);
      af[mi] = *(const short8*)(As + row * 32 + kg * 8);
    }
    short8 bfr[NREP];
#pragma unroll
    for (int ni = 0; ni < NREP; ni++) {
      int col = wc * WN + ni * 16 + (lane & 15);
      int kg = (lane >> 4) ^ (col & 3);
      bfr[ni] = *(const short8*)(Bs + col * 32 + kg * 8);
    }
#pragma unroll
    for (int mi = 0; mi < 4; mi++)
#pragma unroll
      for (int ni = 0; ni < NREP; ni++)
        acc[mi][ni] =
            __builtin_amdgcn_mfma_f32_16x16x32_bf16(af[mi], bfr[ni], acc[mi][ni], 0, 0, 0);
  }
#pragma unroll
  for (int ni = 0; ni < NREP; ni++) {
    int col = n0 + wc * WN + ni * 16 + (lane & 15);
    float bn = bias[col];
#pragma unroll
    for (int mi = 0; mi < 4; mi++) {
      int row0 = m0 + wr * 64 + mi * 16 + (lane >> 4) * 4;
#pragma unroll
      for (int r = 0; r < 4; r++) {
        float v = acc[mi][ni][r] + bn;
        int row = row0 + r;
        if (OUT == 0) {
          ((float*)Cmat)[(size_t)row * N + col] = v;
        } else if (OUT == 1) {
          int bb = row >> 14, p = row & 16383;
          ((float*)Cmat)[((size_t)bb * N + col) * F_HW + p] = v;
        } else {
          ((unsigned short*)Cmat)[(size_t)row * N + col] = f2bf(v);
        }
      }
    }
  }
}

// ---------------- criss-cross logits (bf16 exp output) ----------------
// MODE 0 (H/column): block (w=x, b); E[h,g] = q(h,x)·k(g,x); e[pix(h,x)][g], diag->0
// MODE 1 (W/row):    block (h=x, b); E[w,v] = q(x,w)·k(x,v); e[pix(x,w)][128+v]
template <int MODE>
__global__ __launch_bounds__(256) void cc_logits(const float* __restrict__ qk,
                                                 unsigned short* __restrict__ e) {
  int x = blockIdx.x;
  int b = blockIdx.y;
  size_t base = (size_t)b * F_HW;
  __shared__ float kt[32][132];  // kt[c][g]
  int t = threadIdx.x;
  {
    int gk = t >> 1, c0 = (t & 1) * 16;
    size_t krow = (MODE == 0) ? ((size_t)gk * F_W + x) : ((size_t)x * F_W + gk);
    const float4* src = (const float4*)(qk + (base + krow) * 64 + 32 + c0);
#pragma unroll
    for (int q4 = 0; q4 < 4; q4++) {
      float4 v = src[q4];
      kt[c0 + q4 * 4 + 0][gk] = v.x;
      kt[c0 + q4 * 4 + 1][gk] = v.y;
      kt[c0 + q4 * 4 + 2][gk] = v.z;
      kt[c0 + q4 * 4 + 3][gk] = v.w;
    }
  }
  __syncthreads();
  int i = t >> 1, g0 = (t & 1) * 64;
  size_t qrow = (MODE == 0) ? ((size_t)i * F_W + x) : ((size_t)x * F_W + i);
  const float4* qp = (const float4*)(qk + (base + qrow) * 64);
  float qreg[32];
#pragma unroll
  for (int q4 = 0; q4 < 8; q4++) {
    float4 v = qp[q4];
    qreg[q4 * 4 + 0] = v.x;
    qreg[q4 * 4 + 1] = v.y;
    qreg[q4 * 4 + 2] = v.z;
    qreg[q4 * 4 + 3] = v.w;
  }
  float acc[64];
#pragma unroll
  for (int g = 0; g < 64; g++) acc[g] = 0.0f;
  for (int c = 0; c < 32; c++) {
    float qv = qreg[c];
#pragma unroll
    for (int g = 0; g < 64; g++) acc[g] += qv * kt[c][g0 + g];
  }
  if (MODE == 0) {
    int d = i - g0;
    if (d >= 0 && d < 64) acc[d] = -1e9f;  // diag mask -> exp = 0
  }
  unsigned short* ep = e + (base + qrow) * 256 + MODE * 128 + g0;
#pragma unroll
  for (int g = 0; g < 64; g += 8) {
    short8 pk;
#pragma unroll
    for (int j = 0; j < 8; j++) pk[j] = (short)f2bf(__expf(acc[g + j]));
    *(short8*)(ep + g) = pk;
  }
}

// ---------------- per-pixel reciprocal softmax denominator ----------------
__global__ __launch_bounds__(256) void cc_sums(const unsigned short* __restrict__ e,
                                               float* __restrict__ rsum) {
  int wave = (blockIdx.x * 256 + threadIdx.x) >> 6;
  int lane = threadIdx.x & 63;
  short4v v = *(const short4v*)(e + (size_t)wave * 256 + lane * 4);
  float s = bf2f((unsigned short)v[0]) + bf2f((unsigned short)v[1]) +
            bf2f((unsigned short)v[2]) + bf2f((unsigned short)v[3]);
  s = wred_sum(s);
  if (lane == 0) rsum[wave] = 1.0f / s;
}

// ---------------- criss-cross PV, bf16 MFMA ----------------
// O[i][c] = sum_k Anorm[i][k] * V[k][c] per (x,b) block; 128x256x128.
// MODE 0: i=h (col x fixed), k=g, pix(i)=i*128+x  -> writes po = raw oH (fp32)
// MODE 1: i=w (row x fixed), k=v, pix(i)=x*128+i  -> ccb = bf16(gm*(po+oW)+xt)
template <int MODE>
__global__ __launch_bounds__(256) void cc_pv_mfma(const unsigned short* __restrict__ eb,
                                                  const unsigned short* __restrict__ vtb,
                                                  const float* __restrict__ rsum,
                                                  const float* __restrict__ gamma,
                                                  const float* __restrict__ xt,
                                                  float* __restrict__ po,
                                                  unsigned short* __restrict__ ccb) {
  int x = blockIdx.x, b = blockIdx.y;
  size_t base = (size_t)b * F_HW;
  __shared__ __align__(16) unsigned short As[128 * 128];  // [i][k], swizzled, 32 KB
  __shared__ __align__(16) unsigned short Vs[256 * 64];   // [c][k-chunk], swizzled, 32 KB
  int t = threadIdx.x;
  int wid = t >> 6, lane = t & 63;
  int wr = wid >> 1, wc = wid & 1;
  // ---- stage A = rsum-normalized e (bf16) ----
  {
    int i = t >> 1, half = t & 1;
    size_t pix = (MODE == 0) ? ((size_t)i * F_W + x) : ((size_t)x * F_W + i);
    float rv = rsum[base + pix];
    const unsigned short* ep = eb + (base + pix) * 256 + MODE * 128 + half * 64;
    int g = ((i >> 3) & 7) ^ (i & 7);
#pragma unroll
    for (int s = 0; s < 8; s++) {
      short8 vin = *(const short8*)(ep + s * 8);
      short8 vo;
#pragma unroll
      for (int j = 0; j < 8; j++) vo[j] = (short)f2bf(bf2f((unsigned short)vin[j]) * rv);
      int slot = (half * 8 + s) ^ g;  // g is 3-bit: half bit preserved
      *(short8*)(As + i * 128 + slot * 8) = vo;
    }
  }
  float4v acc[4][8] = {};
#pragma unroll
  for (int kc = 0; kc < 2; kc++) {
    __syncthreads();
    // ---- stage Vs[c][k] for k-chunk kc: in-register 8x8 transpose ----
    {
      int ko = t >> 5, cj = t & 31;
      short8 rowv[8];
#pragma unroll
      for (int r = 0; r < 8; r++) {
        int kk = kc * 64 + ko * 8 + r;
        size_t pixk = (MODE == 0) ? ((size_t)kk * F_W + x) : ((size_t)x * F_W + kk);
        rowv[r] = *(const short8*)(vtb + (base + pixk) * 256 + cj * 8);
      }
#pragma unroll
      for (int j = 0; j < 8; j++) {
        short8 col;
#pragma unroll
        for (int r = 0; r < 8; r++) col[r] = rowv[r][j];
        int c = cj * 8 + j;
        int slot = ko ^ ((c >> 3) & 7) ^ (c & 7);
        *(short8*)(Vs + c * 64 + slot * 8) = col;
      }
    }
    __syncthreads();
#pragma unroll
    for (int ksub = 0; ksub < 2; ksub++) {
      short8 af[4];
#pragma unroll
      for (int mi = 0; mi < 4; mi++) {
        int i = wr * 64 + mi * 16 + (lane & 15);
        int slot = (kc * 8 + ksub * 4 + (lane >> 4)) ^ ((i >> 3) & 7) ^ (i & 7);
        af[mi] = *(const short8*)(As + i * 128 + slot * 8);
      }
      short8 bfv[8];
#pragma unroll
      for (int ni = 0; ni < 8; ni++) {
        int c = wc * 128 + ni * 16 + (lane & 15);
        int slot = (ksub * 4 + (lane >> 4)) ^ ((c >> 3) & 7) ^ (c & 7);
        bfv[ni] = *(const short8*)(Vs + c * 64 + slot * 8);
      }
#pragma unroll
      for (int mi = 0; mi < 4; mi++)
#pragma unroll
        for (int ni = 0; ni < 8; ni++)
          acc[mi][ni] =
              __builtin_amdgcn_mfma_f32_16x16x32_bf16(af[mi], bfv[ni], acc[mi][ni], 0, 0, 0);
    }
  }
  // ---- epilogue ----
  float gm = gamma[0];
#pragma unroll
  for (int mi = 0; mi < 4; mi++) {
#pragma unroll
    for (int ni = 0; ni < 8; ni++) {
#pragma unroll
      for (int r = 0; r < 4; r++) {
        int i = wr * 64 + mi * 16 + (lane >> 4) * 4 + r;
        int c = wc * 128 + ni * 16 + (lane & 15);
        size_t pix = (MODE == 0) ? ((size_t)i * F_W + x) : ((size_t)x * F_W + i);
        size_t idx = (base + pix) * 256 + c;
        if (MODE == 0) {
          po[idx] = acc[mi][ni][r];
        } else {
          float v = gm * (po[idx] + acc[mi][ni][r]) + xt[idx];
          ccb[idx] = f2bf(v);
        }
      }
    }
  }
}

// ---------------- window attention (chunked), bf16 in/out ----------------
__global__ __launch_bounds__(256) void win_attn(const unsigned short* __restrict__ qkv,
                                                int win0, long long pix_base,
                                                const float* __restrict__ logit_scale,
                                                const float* __restrict__ tblS,
                                                unsigned short* __restrict__ out) {
  int win = win0 + blockIdx.x;  // global window id 0..2047
  int hh = blockIdx.y;          // head
  int b = win >> 8;
  int wy = (win >> 4) & 15, wx = win & 15;
  __shared__ float qs[64][36];
  __shared__ float ks[64][36];
  __shared__ float vs[64][32];
  __shared__ float att[64][65];
  int t = threadIdx.x;
  int n = t >> 2, d0 = (t & 3) * 8;
  {
    int iy = n >> 3, ix = n & 7;
    size_t pglob = (size_t)b * F_HW + (size_t)(wy * 8 + iy) * F_W + wx * 8 + ix;
    size_t qoff = (pglob - (size_t)pix_base) * 768 + hh * 32 + d0;
#pragma unroll
    for (int i = 0; i < 8; i++) qs[n][d0 + i] = bf2f(qkv[qoff + i]);
#pragma unroll
    for (int i = 0; i < 8; i++) ks[n][d0 + i] = bf2f(qkv[qoff + 256 + i]);
#pragma unroll
    for (int i = 0; i < 8; i++) vs[n][d0 + i] = bf2f(qkv[qoff + 512 + i]);
  }
  __syncthreads();
  if (t < 128) {
    float* rowp = (t < 64) ? qs[t] : ks[t - 64];
    float ss = 0.0f;
#pragma unroll
    for (int i = 0; i < 32; i++) ss += rowp[i] * rowp[i];
    float inv = 1.0f / fmaxf(sqrtf(ss), 1e-12f);
#pragma unroll
    for (int i = 0; i < 32; i++) rowp[i] *= inv;
  }
  __syncthreads();
  float scale = __expf(fminf(logit_scale[hh], 4.605170185988091f));  // ln(100)
  int i = t >> 2;
  int iy = i >> 3, ix = i & 7;
#pragma unroll 4
  for (int jj = 0; jj < 16; jj++) {
    int j = (t & 3) * 16 + jj;
    float s = 0.0f;
#pragma unroll
    for (int d = 0; d < 32; d++) s += qs[i][d] * ks[j][d];
    int jy = j >> 3, jx = j & 7;
    int e = (iy - jy + 7) * 15 + (ix - jx + 7);
    att[i][j] = s * scale + tblS[e * 8 + hh];
  }
  float mx = -1e30f;
#pragma unroll 4
  for (int jj = 0; jj < 16; jj++) mx = fmaxf(mx, att[i][(t & 3) * 16 + jj]);
  mx = fmaxf(mx, __shfl_xor(mx, 1));
  mx = fmaxf(mx, __shfl_xor(mx, 2));
  float sm = 0.0f;
#pragma unroll 4
  for (int jj = 0; jj < 16; jj++) {
    float e2 = __expf(att[i][(t & 3) * 16 + jj] - mx);
    att[i][(t & 3) * 16 + jj] = e2;
    sm += e2;
  }
  sm += __shfl_xor(sm, 1);
  sm += __shfl_xor(sm, 2);
  float inv = 1.0f / sm;
#pragma unroll 4
  for (int jj = 0; jj < 16; jj++) att[i][(t & 3) * 16 + jj] *= inv;
  __syncthreads();
  float o[8] = {};
  int dbase = (t & 3) * 8;
  for (int j = 0; j < 64; j++) {
    float aij = att[i][j];
#pragma unroll
    for (int dd = 0; dd < 8; dd++) o[dd] += aij * vs[j][dbase + dd];
  }
  size_t orow =
      ((size_t)b * F_HW + (size_t)(wy * 8 + iy) * F_W + wx * 8 + ix) * 256 + hh * 32 + dbase;
  short8 pk;
#pragma unroll
  for (int dd = 0; dd < 8; dd++) pk[dd] = (short)f2bf(o[dd]);
  *(short8*)(out + orow) = pk;
}

// ---------------- launch ----------------
extern "C" void kernel_launch(void* const* d_in, const int* in_sizes, int n_in,
                              void* d_out, int out_size, void* d_ws, size_t ws_size,
                              hipStream_t stream) {
  const float* x = (const float*)d_in[0];
  const float* y = (const float*)d_in[1];
  const float* Wq = (const float*)d_in[2];
  const float* bq = (const float*)d_in[3];
  const float* Wk = (const float*)d_in[4];
  const float* bk = (const float*)d_in[5];
  const float* Wv = (const float*)d_in[6];
  const float* bv = (const float*)d_in[7];
  const float* gamma = (const float*)d_in[8];
  const float* qkv_w = (const float*)d_in[9];
  const float* q_bias = (const float*)d_in[10];
  const float* v_bias = (const float*)d_in[11];
  const float* logit_scale = (const float*)d_in[12];
  const float* cpb_w1 = (const float*)d_in[13];
  const float* cpb_b1 = (const float*)d_in[14];
  const float* cpb_w2 = (const float*)d_in[15];
  const float* proj_w = (const float*)d_in[16];
  const float* proj_b = (const float*)d_in[17];

  float* ws = (float*)d_ws;
  const size_t NPX = (size_t)F_B * F_HW;  // 131072
  const size_t M1 = NPX * 256;            // 33.55M
  // regions (float offsets):
  size_t f_xt = 0;                   // xt fp32 (33.5M f); later attn_b bf16 overlay
  size_t f_eb = M1;                  // ytb bf16 earlier; eb bf16 later (16.8M f)
  size_t f_vtb = M1 + M1 / 2;        // xb bf16 earlier; vtb bf16 later (16.8M f)
  size_t f_po = 2 * M1;              // po fp32 (33.5M f); later qkvchunk bf16 (12.6M f)
  size_t f_ccb = 3 * M1;             // ccb bf16 (16.8M f)
  size_t f_qkb = 3 * M1 + M1 / 2;    // qkb fp32 (NPX*64 = 8.4M f)
  size_t f_wts = f_qkb + NPX * 64;
  size_t o_qkwb = f_wts;              // 16384 ushort -> 8192 f
  size_t o_Wvb = o_qkwb + 8192;       // 65536 ushort -> 32768 f
  size_t o_qkvwb = o_Wvb + 32768;     // 196608 ushort -> 98304 f
  size_t o_projwb = o_qkvwb + 98304;  // 65536 ushort -> 32768 f
  size_t o_qkb2 = o_projwb + 32768;   // 64 f
  size_t o_qkvb2 = o_qkb2 + 64;       // 768 f
  size_t o_tbl = o_qkvb2 + 768;       // 1800 f
  size_t o_rsum = o_tbl + 1800;       // NPX f
  size_t need = (o_rsum + NPX) * sizeof(float);
  if (ws_size < need) {
    fprintf(stderr, "kernel_launch: ws too small: %zu < %zu\n", ws_size, need);
    return;
  }
  float* xt = ws + f_xt;
  unsigned short* attn_b = (unsigned short*)(ws + f_xt);
  unsigned short* ytb = (unsigned short*)(ws + f_eb);
  unsigned short* eb = (unsigned short*)(ws + f_eb);
  unsigned short* xb = (unsigned short*)(ws + f_vtb);
  unsigned short* vtb = (unsigned short*)(ws + f_vtb);
  float* po = ws + f_po;
  unsigned short* qkvchunk = (unsigned short*)(ws + f_po);
  unsigned short* ccb = (unsigned short*)(ws + f_ccb);
  float* qkb = ws + f_qkb;
  unsigned short* qk_wb = (unsigned short*)(ws + o_qkwb);
  unsigned short* Wvb = (unsigned short*)(ws + o_Wvb);
  unsigned short* qkv_wb = (unsigned short*)(ws + o_qkvwb);
  unsigned short* proj_wb = (unsigned short*)(ws + o_projwb);
  float* qk_b = ws + o_qkb2;
  float* qkv_b = ws + o_qkvb2;
  float* tblS = ws + o_tbl;
  float* rsum = ws + o_rsum;

  build_aux2<<<dim3(768), dim3(256), 0, stream>>>(Wq, Wk, bq, bk, q_bias, v_bias, Wv, qkv_w,
                                                  proj_w, qk_wb, qk_b, qkv_b, Wvb, qkv_wb,
                                                  proj_wb);
  cpb_table<<<dim3(225), dim3(256), 0, stream>>>(cpb_w1, cpb_b1, cpb_w2, tblS);
  // x^T -> xt fp32 + xb bf16 ; y^T -> ytb bf16
  transpose_x<<<dim3(512, 8, 8), dim3(32, 8), 0, stream>>>(x, xt, xb);
  transpose_y<<<dim3(512, 8, 8), dim3(32, 8), 0, stream>>>(y, ytb);
  // q|k projection: (BHW x 256) @ (64 x 256)^T -> fp32
  gemm_mfma<64, 0><<<dim3(1, 1024), dim3(256), 0, stream>>>(xb, qk_wb, qk_b, qkb, (int)NPX,
                                                            64);
  // v projection -> bf16 vtb
  gemm_mfma<128, 2><<<dim3(2, 1024), dim3(256), 0, stream>>>(ytb, Wvb, bv, vtb, (int)NPX, 256);
  // criss-cross attention (GEMM-structured, bf16 e)
  cc_logits<0><<<dim3(128, 8), dim3(256), 0, stream>>>(qkb, eb);
  cc_logits<1><<<dim3(128, 8), dim3(256), 0, stream>>>(qkb, eb);
  cc_sums<<<dim3(32768), dim3(256), 0, stream>>>(eb, rsum);
  cc_pv_mfma<0><<<dim3(128, 8), dim3(256), 0, stream>>>(eb, vtb, rsum, gamma, xt, po, ccb);
  cc_pv_mfma<1><<<dim3(128, 8), dim3(256), 0, stream>>>(eb, vtb, rsum, gamma, xt, po, ccb);
  // window qkv projection + attention, chunked: 4 chunks x 2 batches (32768 rows)
  for (int c = 0; c < 4; c++) {
    const unsigned short* ccA = ccb + (size_t)c * 32768 * 256;
    gemm_mfma<128, 2><<<dim3(6, 256), dim3(256), 0, stream>>>(ccA, qkv_wb, qkv_b, qkvchunk,
                                                              32768, 768);
    win_attn<<<dim3(512, 8), dim3(256), 0, stream>>>(qkvchunk, c * 512, (long long)c * 32768,
                                                     logit_scale, tblS, attn_b);
  }
  // output projection with transposed (B,C,H,W) write
  gemm_mfma<128, 1><<<dim3(2, 1024), dim3(256), 0, stream>>>(attn_b, proj_wb, proj_b, d_out,
                                                             (int)NPX, 256);
}

// Round 6
// 700.686 us; speedup vs baseline: 6.1573x; 1.4512x over previous
//
#include <hip/hip_runtime.h>
#include <cstdio>
#include <cstddef>
#include <cstdint>

#define F_B 8
#define F_C 256
#define F_H 128
#define F_W 128
#define F_HW 16384

typedef __attribute__((ext_vector_type(8))) short short8;   // bf16x8 MFMA operand
typedef __attribute__((ext_vector_type(4))) short short4v;  // bf16x4
typedef __attribute__((ext_vector_type(4))) float float4v;  // MFMA accumulator

__device__ __forceinline__ float wred_sum(float v) {
#pragma unroll
  for (int o = 1; o < 64; o <<= 1) v += __shfl_xor(v, o);
  return v;
}

__device__ __forceinline__ unsigned short f2bf(float f) {
  union {
    float f;
    uint32_t u;
  } v;
  v.f = f;
  return (unsigned short)((v.u + 0x7fffu + ((v.u >> 16) & 1u)) >> 16);
}

__device__ __forceinline__ float bf2f(unsigned short u) {
  union {
    uint32_t u;
    float f;
  } v;
  v.u = ((uint32_t)u) << 16;
  return v.f;
}

__device__ __forceinline__ void async_copy16(const unsigned short* g, unsigned short* l) {
  __builtin_amdgcn_global_load_lds((const __attribute__((address_space(1))) void*)g,
                                   (__attribute__((address_space(3))) void*)l, 16, 0, 0);
}

// ---------------- aux: weight bf16 conversion + bias concat ----------------
__global__ void build_aux2(const float* __restrict__ Wq, const float* __restrict__ Wk,
                           const float* __restrict__ bq, const float* __restrict__ bk,
                           const float* __restrict__ q_bias, const float* __restrict__ v_bias,
                           const float* __restrict__ Wv, const float* __restrict__ qkv_w,
                           const float* __restrict__ proj_w, unsigned short* __restrict__ qk_wb,
                           float* __restrict__ qk_b, float* __restrict__ qkv_b,
                           unsigned short* __restrict__ Wvb, unsigned short* __restrict__ qkv_wb,
                           unsigned short* __restrict__ proj_wb) {
  int t = blockIdx.x * 256 + threadIdx.x;  // 768 blocks -> 196608 threads
  if (t < 8192) {
    qk_wb[t] = f2bf(Wq[t]);
    qk_wb[8192 + t] = f2bf(Wk[t]);
  }
  if (t < 65536) {
    Wvb[t] = f2bf(Wv[t]);
    proj_wb[t] = f2bf(proj_w[t]);
  }
  if (t < 196608) qkv_wb[t] = f2bf(qkv_w[t]);
  if (t < 32) {
    qk_b[t] = bq[t];
    qk_b[32 + t] = bk[t];
  }
  if (t < 256) {
    qkv_b[t] = q_bias[t];
    qkv_b[256 + t] = 0.0f;
    qkv_b[512 + t] = v_bias[t];
  }
}

// ---------------- CPB MLP table: tblS[225][8] = 16*sigmoid(mlp(coords)) -----
__device__ __forceinline__ float cpb_coord(int a) {
  float v = (float)(a - 7) * (8.0f / 7.0f);
  float lg = log2f(fabsf(v) + 1.0f) * (1.0f / 3.0f);  // /log2(8)
  return (v < 0.0f) ? -lg : lg;
}

__global__ void cpb_table(const float* __restrict__ w1, const float* __restrict__ b1,
                          const float* __restrict__ w2, float* __restrict__ tblS) {
  int e = blockIdx.x;  // 0..224
  int yi = e / 15, xi = e % 15;
  float ry = cpb_coord(yi), rx = cpb_coord(xi);
  __shared__ float hid[512];
  int t = threadIdx.x;  // 256
  for (int j = t; j < 512; j += 256) {
    float hv = w1[j * 2] * ry + w1[j * 2 + 1] * rx + b1[j];
    hid[j] = fmaxf(hv, 0.0f);
  }
  __syncthreads();
  if (t < 8) {
    float s = 0.0f;
    for (int j = 0; j < 512; j++) s += hid[j] * w2[t * 512 + j];
    tblS[e * 8 + t] = 16.0f / (1.0f + __expf(-s));
  }
}

// ---------------- rpbt[h][i][j] = tblS[e(i,j)*8+h]  (window-independent) ----
__global__ void build_rpbt(const float* __restrict__ tblS, float* __restrict__ rpbt) {
  int t = blockIdx.x * 256 + threadIdx.x;  // < 32768
  int h = t >> 12, i = (t >> 6) & 63, j = t & 63;
  int e = ((i >> 3) - (j >> 3) + 7) * 15 + ((i & 7) - (j & 7) + 7);
  rpbt[t] = tblS[e * 8 + h];
}

// ---------------- transpose (B,C,HW) -> (B,HW,C); fp32 + bf16 dual ---------
__global__ void transpose_x(const float* __restrict__ in, float* __restrict__ outf,
                            unsigned short* __restrict__ outb) {
  __shared__ float tile[32][33];
  int b = blockIdx.z;
  int p0 = blockIdx.x * 32;
  int c0 = blockIdx.y * 32;
  const float* src = in + (size_t)b * F_C * F_HW;
  int tx = threadIdx.x, ty = threadIdx.y;  // 32 x 8
#pragma unroll
  for (int i = 0; i < 4; i++) {
    tile[ty + i * 8][tx] = src[(size_t)(c0 + ty + i * 8) * F_HW + p0 + tx];
  }
  __syncthreads();
#pragma unroll
  for (int i = 0; i < 4; i++) {
    size_t idx = (size_t)b * F_HW * F_C + (size_t)(p0 + ty + i * 8) * F_C + c0 + tx;
    float v = tile[tx][ty + i * 8];
    outf[idx] = v;
    outb[idx] = f2bf(v);
  }
}

__global__ void transpose_y(const float* __restrict__ in, unsigned short* __restrict__ outb) {
  __shared__ float tile[32][33];
  int b = blockIdx.z;
  int p0 = blockIdx.x * 32;
  int c0 = blockIdx.y * 32;
  const float* src = in + (size_t)b * F_C * F_HW;
  int tx = threadIdx.x, ty = threadIdx.y;  // 32 x 8
#pragma unroll
  for (int i = 0; i < 4; i++) {
    tile[ty + i * 8][tx] = src[(size_t)(c0 + ty + i * 8) * F_HW + p0 + tx];
  }
  __syncthreads();
#pragma unroll
  for (int i = 0; i < 4; i++) {
    size_t idx = (size_t)b * F_HW * F_C + (size_t)(p0 + ty + i * 8) * F_C + c0 + tx;
    outb[idx] = f2bf(tile[tx][ty + i * 8]);
  }
}

// ---------------- bf16 MFMA GEMM: C[M,N] = A[M,256] @ W[N,256]^T + bias ----
// OUT 0: fp32 row-major. OUT 1: fp32 out[((row>>14)*N+col)*16384+(row&16383)].
// OUT 2: bf16 row-major.
template <int BN, int OUT>
__global__ __launch_bounds__(256) void gemm_mfma(const unsigned short* __restrict__ A,
                                                 const unsigned short* __restrict__ Wt,
                                                 const float* __restrict__ bias, void* Cmat,
                                                 int M, int N) {
  constexpr int WN = BN / 2;
  constexpr int NREP = WN / 16;
  __shared__ __align__(16) unsigned short As[128 * 32];
  __shared__ __align__(16) unsigned short Bs[BN * 32];
  int m0 = blockIdx.y * 128;
  int n0 = blockIdx.x * BN;
  int t = threadIdx.x;
  int wid = t >> 6, lane = t & 63;
  int wr = wid >> 1, wc = wid & 1;

  float4v acc[4][NREP] = {};

  for (int k0 = 0; k0 < 256; k0 += 32) {
    __syncthreads();
#pragma unroll
    for (int j = 0; j < 2; j++) {
      int r = wid * 32 + j * 16 + (lane >> 2);
      int kg = (lane & 3) ^ (r & 3);  // inverse swizzle on global source
      const unsigned short* gp = A + (size_t)(m0 + r) * 256 + k0 + kg * 8;
      async_copy16(gp, As + (wid * 32 + j * 16) * 32);
    }
#pragma unroll
    for (int j = 0; j < BN / 64; j++) {
      int r = wid * (BN / 4) + j * 16 + (lane >> 2);
      int kg = (lane & 3) ^ (r & 3);
      const unsigned short* gp = Wt + (size_t)(n0 + r) * 256 + k0 + kg * 8;
      async_copy16(gp, Bs + (wid * (BN / 4) + j * 16) * 32);
    }
    __syncthreads();
    short8 af[4];
#pragma unroll
    for (int mi = 0; mi < 4; mi++) {
      int row = wr * 64 + mi * 16 + (lane & 15);
      int kg = (lane >> 4) ^ (row & 3);
      af[mi] = *(const short8*)(As + row * 32 + kg * 8);
    }
    short8 bfr[NREP];
#pragma unroll
    for (int ni = 0; ni < NREP; ni++) {
      int col = wc * WN + ni * 16 + (lane & 15);
      int kg = (lane >> 4) ^ (col & 3);
      bfr[ni] = *(const short8*)(Bs + col * 32 + kg * 8);
    }
#pragma unroll
    for (int mi = 0; mi < 4; mi++)
#pragma unroll
      for (int ni = 0; ni < NREP; ni++)
        acc[mi][ni] =
            __builtin_amdgcn_mfma_f32_16x16x32_bf16(af[mi], bfr[ni], acc[mi][ni], 0, 0, 0);
  }
#pragma unroll
  for (int ni = 0; ni < NREP; ni++) {
    int col = n0 + wc * WN + ni * 16 + (lane & 15);
    float bn = bias[col];
#pragma unroll
    for (int mi = 0; mi < 4; mi++) {
      int row0 = m0 + wr * 64 + mi * 16 + (lane >> 4) * 4;
#pragma unroll
      for (int r = 0; r < 4; r++) {
        float v = acc[mi][ni][r] + bn;
        int row = row0 + r;
        if (OUT == 0) {
          ((float*)Cmat)[(size_t)row * N + col] = v;
        } else if (OUT == 1) {
          int bb = row >> 14, p = row & 16383;
          ((float*)Cmat)[((size_t)bb * N + col) * F_HW + p] = v;
        } else {
          ((unsigned short*)Cmat)[(size_t)row * N + col] = f2bf(v);
        }
      }
    }
  }
}

// ---------------- criss-cross logits (bf16 exp output) ----------------
template <int MODE>
__global__ __launch_bounds__(256) void cc_logits(const float* __restrict__ qk,
                                                 unsigned short* __restrict__ e) {
  int x = blockIdx.x;
  int b = blockIdx.y;
  size_t base = (size_t)b * F_HW;
  __shared__ float kt[32][132];  // kt[c][g]
  int t = threadIdx.x;
  {
    int gk = t >> 1, c0 = (t & 1) * 16;
    size_t krow = (MODE == 0) ? ((size_t)gk * F_W + x) : ((size_t)x * F_W + gk);
    const float4* src = (const float4*)(qk + (base + krow) * 64 + 32 + c0);
#pragma unroll
    for (int q4 = 0; q4 < 4; q4++) {
      float4 v = src[q4];
      kt[c0 + q4 * 4 + 0][gk] = v.x;
      kt[c0 + q4 * 4 + 1][gk] = v.y;
      kt[c0 + q4 * 4 + 2][gk] = v.z;
      kt[c0 + q4 * 4 + 3][gk] = v.w;
    }
  }
  __syncthreads();
  int i = t >> 1, g0 = (t & 1) * 64;
  size_t qrow = (MODE == 0) ? ((size_t)i * F_W + x) : ((size_t)x * F_W + i);
  const float4* qp = (const float4*)(qk + (base + qrow) * 64);
  float qreg[32];
#pragma unroll
  for (int q4 = 0; q4 < 8; q4++) {
    float4 v = qp[q4];
    qreg[q4 * 4 + 0] = v.x;
    qreg[q4 * 4 + 1] = v.y;
    qreg[q4 * 4 + 2] = v.z;
    qreg[q4 * 4 + 3] = v.w;
  }
  float acc[64];
#pragma unroll
  for (int g = 0; g < 64; g++) acc[g] = 0.0f;
  for (int c = 0; c < 32; c++) {
    float qv = qreg[c];
#pragma unroll
    for (int g = 0; g < 64; g++) acc[g] += qv * kt[c][g0 + g];
  }
  if (MODE == 0) {
    int d = i - g0;
    if (d >= 0 && d < 64) acc[d] = -1e9f;  // diag mask -> exp = 0
  }
  unsigned short* ep = e + (base + qrow) * 256 + MODE * 128 + g0;
#pragma unroll
  for (int g = 0; g < 64; g += 8) {
    short8 pk;
#pragma unroll
    for (int j = 0; j < 8; j++) pk[j] = (short)f2bf(__expf(acc[g + j]));
    *(short8*)(ep + g) = pk;
  }
}

// ---------------- per-pixel reciprocal softmax denominator ----------------
__global__ __launch_bounds__(256) void cc_sums(const unsigned short* __restrict__ e,
                                               float* __restrict__ rsum) {
  int wave = (blockIdx.x * 256 + threadIdx.x) >> 6;
  int lane = threadIdx.x & 63;
  short4v v = *(const short4v*)(e + (size_t)wave * 256 + lane * 4);
  float s = bf2f((unsigned short)v[0]) + bf2f((unsigned short)v[1]) +
            bf2f((unsigned short)v[2]) + bf2f((unsigned short)v[3]);
  s = wred_sum(s);
  if (lane == 0) rsum[wave] = 1.0f / s;
}

// ---------------- criss-cross PV, bf16 MFMA ----------------
template <int MODE>
__global__ __launch_bounds__(256) void cc_pv_mfma(const unsigned short* __restrict__ eb,
                                                  const unsigned short* __restrict__ vtb,
                                                  const float* __restrict__ rsum,
                                                  const float* __restrict__ gamma,
                                                  const float* __restrict__ xt,
                                                  float* __restrict__ po,
                                                  unsigned short* __restrict__ ccb) {
  int x = blockIdx.x, b = blockIdx.y;
  size_t base = (size_t)b * F_HW;
  __shared__ __align__(16) unsigned short As[128 * 128];  // [i][k], swizzled, 32 KB
  __shared__ __align__(16) unsigned short Vs[256 * 64];   // [c][k-chunk], swizzled, 32 KB
  int t = threadIdx.x;
  int wid = t >> 6, lane = t & 63;
  int wr = wid >> 1, wc = wid & 1;
  // ---- stage A = rsum-normalized e (bf16) ----
  {
    int i = t >> 1, half = t & 1;
    size_t pix = (MODE == 0) ? ((size_t)i * F_W + x) : ((size_t)x * F_W + i);
    float rv = rsum[base + pix];
    const unsigned short* ep = eb + (base + pix) * 256 + MODE * 128 + half * 64;
    int g = ((i >> 3) & 7) ^ (i & 7);
#pragma unroll
    for (int s = 0; s < 8; s++) {
      short8 vin = *(const short8*)(ep + s * 8);
      short8 vo;
#pragma unroll
      for (int j = 0; j < 8; j++) vo[j] = (short)f2bf(bf2f((unsigned short)vin[j]) * rv);
      int slot = (half * 8 + s) ^ g;  // g is 3-bit: half bit preserved
      *(short8*)(As + i * 128 + slot * 8) = vo;
    }
  }
  float4v acc[4][8] = {};
#pragma unroll
  for (int kc = 0; kc < 2; kc++) {
    __syncthreads();
    // ---- stage Vs[c][k] for k-chunk kc: in-register 8x8 transpose ----
    {
      int ko = t >> 5, cj = t & 31;
      short8 rowv[8];
#pragma unroll
      for (int r = 0; r < 8; r++) {
        int kk = kc * 64 + ko * 8 + r;
        size_t pixk = (MODE == 0) ? ((size_t)kk * F_W + x) : ((size_t)x * F_W + kk);
        rowv[r] = *(const short8*)(vtb + (base + pixk) * 256 + cj * 8);
      }
#pragma unroll
      for (int j = 0; j < 8; j++) {
        short8 col;
#pragma unroll
        for (int r = 0; r < 8; r++) col[r] = rowv[r][j];
        int c = cj * 8 + j;
        int slot = ko ^ ((c >> 3) & 7) ^ (c & 7);
        *(short8*)(Vs + c * 64 + slot * 8) = col;
      }
    }
    __syncthreads();
#pragma unroll
    for (int ksub = 0; ksub < 2; ksub++) {
      short8 af[4];
#pragma unroll
      for (int mi = 0; mi < 4; mi++) {
        int i = wr * 64 + mi * 16 + (lane & 15);
        int slot = (kc * 8 + ksub * 4 + (lane >> 4)) ^ ((i >> 3) & 7) ^ (i & 7);
        af[mi] = *(const short8*)(As + i * 128 + slot * 8);
      }
      short8 bfv[8];
#pragma unroll
      for (int ni = 0; ni < 8; ni++) {
        int c = wc * 128 + ni * 16 + (lane & 15);
        int slot = (ksub * 4 + (lane >> 4)) ^ ((c >> 3) & 7) ^ (c & 7);
        bfv[ni] = *(const short8*)(Vs + c * 64 + slot * 8);
      }
#pragma unroll
      for (int mi = 0; mi < 4; mi++)
#pragma unroll
        for (int ni = 0; ni < 8; ni++)
          acc[mi][ni] =
              __builtin_amdgcn_mfma_f32_16x16x32_bf16(af[mi], bfv[ni], acc[mi][ni], 0, 0, 0);
    }
  }
  // ---- epilogue ----
  float gm = gamma[0];
#pragma unroll
  for (int mi = 0; mi < 4; mi++) {
#pragma unroll
    for (int ni = 0; ni < 8; ni++) {
#pragma unroll
      for (int r = 0; r < 4; r++) {
        int i = wr * 64 + mi * 16 + (lane >> 4) * 4 + r;
        int c = wc * 128 + ni * 16 + (lane & 15);
        size_t pix = (MODE == 0) ? ((size_t)i * F_W + x) : ((size_t)x * F_W + i);
        size_t idx = (base + pix) * 256 + c;
        if (MODE == 0) {
          po[idx] = acc[mi][ni][r];
        } else {
          float v = gm * (po[idx] + acc[mi][ni][r]) + xt[idx];
          ccb[idx] = f2bf(v);
        }
      }
    }
  }
}

// ---------------- window attention, MFMA: 1 wave per (window, head) --------
// qkv: [NPX][768] bf16 (q|k|v, head-major 32). out: [NPX][256] bf16.
// rpbt: [8][64][64] fp32 = 16*sigmoid(cpb) per (head, i, j).
__global__ __launch_bounds__(256) void win_attn_mfma(const unsigned short* __restrict__ qkv,
                                                     const float* __restrict__ logit_scale,
                                                     const float* __restrict__ rpbt,
                                                     unsigned short* __restrict__ out) {
  __shared__ __align__(16) unsigned short Pl[4][4096];  // per-wave P[i][j] bf16, swizzled
  __shared__ __align__(16) unsigned short Vt[4][2048];  // per-wave V^T[d][j] bf16, swizzled
  int win = blockIdx.x;
  int wid = threadIdx.x >> 6, lane = threadIdx.x & 63;
  int hh = blockIdx.y * 4 + wid;
  int b = win >> 8, wy = (win >> 4) & 15, wx = win & 15;
  size_t pbase = (size_t)b * F_HW + (size_t)(wy * 8) * F_W + wx * 8;
  int il = lane & 15, kg = lane >> 4;

  // ---- load + cosine-normalize Q (B-frags) and K (A-frags) ----
  short8 qb[4], ka[4];
#pragma unroll
  for (int ni = 0; ni < 4; ni++) {
    int i = ni * 16 + il;
    size_t row = (pbase + (size_t)(i >> 3) * F_W + (i & 7)) * 768 + hh * 32 + kg * 8;
    short8 qv = *(const short8*)(qkv + row);
    short8 kv = *(const short8*)(qkv + row + 256);
    float qss = 0.0f, kss = 0.0f;
#pragma unroll
    for (int j = 0; j < 8; j++) {
      float qf = bf2f((unsigned short)qv[j]);
      float kf = bf2f((unsigned short)kv[j]);
      qss += qf * qf;
      kss += kf * kf;
    }
    qss += __shfl_xor(qss, 16);
    qss += __shfl_xor(qss, 32);
    kss += __shfl_xor(kss, 16);
    kss += __shfl_xor(kss, 32);
    float qinv = 1.0f / fmaxf(sqrtf(qss), 1e-12f);
    float kinv = 1.0f / fmaxf(sqrtf(kss), 1e-12f);
#pragma unroll
    for (int j = 0; j < 8; j++) {
      qb[ni][j] = (short)f2bf(bf2f((unsigned short)qv[j]) * qinv);
      ka[ni][j] = (short)f2bf(bf2f((unsigned short)kv[j]) * kinv);
    }
  }

  // ---- stage V^T[d][j] (lanes 0..31, in-register 8x8 transpose) ----
  if (lane < 32) {
    int jb = lane >> 2, db = lane & 3;
    short8 rows[8];
#pragma unroll
    for (int r = 0; r < 8; r++) {
      rows[r] =
          *(const short8*)(qkv + (pbase + (size_t)jb * F_W + r) * 768 + hh * 32 + 512 + db * 8);
    }
#pragma unroll
    for (int c = 0; c < 8; c++) {
      int d = db * 8 + c;
      short8 col;
#pragma unroll
      for (int r = 0; r < 8; r++) col[r] = rows[r][c];
      *(short8*)(Vt[wid] + d * 64 + ((jb ^ (d & 7)) * 8)) = col;
    }
  }

  // ---- S^T = K @ Q^T (D[j][i]) ----
  float4v sacc[4][4] = {};
#pragma unroll
  for (int mj = 0; mj < 4; mj++)
#pragma unroll
    for (int ni = 0; ni < 4; ni++)
      sacc[mj][ni] = __builtin_amdgcn_mfma_f32_16x16x32_bf16(ka[mj], qb[ni], sacc[mj][ni], 0, 0, 0);

  float scale = __expf(fminf(logit_scale[hh], 4.605170185988091f));  // ln(100)

  // ---- softmax over j (per col i), write P[i][j] bf16 to LDS ----
#pragma unroll
  for (int ni = 0; ni < 4; ni++) {
    int i = ni * 16 + il;
    const float* rp = rpbt + ((size_t)hh * 64 + i) * 64;
    float sv[16];
    float mx = -1e30f;
#pragma unroll
    for (int mj = 0; mj < 4; mj++) {
      float4 rb = *(const float4*)(rp + mj * 16 + kg * 4);
      float rbs[4] = {rb.x, rb.y, rb.z, rb.w};
#pragma unroll
      for (int r = 0; r < 4; r++) {
        float v = sacc[mj][ni][r] * scale + rbs[r];
        sv[mj * 4 + r] = v;
        mx = fmaxf(mx, v);
      }
    }
    mx = fmaxf(mx, __shfl_xor(mx, 16));
    mx = fmaxf(mx, __shfl_xor(mx, 32));
    float sm = 0.0f;
#pragma unroll
    for (int u = 0; u < 16; u++) {
      sv[u] = __expf(sv[u] - mx);
      sm += sv[u];
    }
    sm += __shfl_xor(sm, 16);
    sm += __shfl_xor(sm, 32);
    float inv = 1.0f / sm;
#pragma unroll
    for (int mj = 0; mj < 4; mj++) {
      int j0 = mj * 16 + kg * 4;
      short4v pk;
#pragma unroll
      for (int r = 0; r < 4; r++) pk[r] = (short)f2bf(sv[mj * 4 + r] * inv);
      int byteoff = i * 128 + (((j0 >> 3) ^ (i & 7)) * 16) + (j0 & 7) * 2;
      *(short4v*)((char*)Pl[wid] + byteoff) = pk;
    }
  }
  __syncthreads();

  // ---- O^T = V^T @ P^T: A = V^T[d][j], B[k=j][n=i] = P[i][j] ----
  float4v oacc[2][4] = {};
#pragma unroll
  for (int kc = 0; kc < 2; kc++) {
    short8 va[2];
#pragma unroll
    for (int md = 0; md < 2; md++) {
      int d = md * 16 + il;
      va[md] = *(const short8*)((char*)Vt[wid] + d * 128 + (((kc * 4 + kg) ^ (d & 7)) * 16));
    }
    short8 pb[4];
#pragma unroll
    for (int ni = 0; ni < 4; ni++) {
      int i = ni * 16 + il;
      pb[ni] = *(const short8*)((char*)Pl[wid] + i * 128 + (((kc * 4 + kg) ^ (i & 7)) * 16));
    }
#pragma unroll
    for (int md = 0; md < 2; md++)
#pragma unroll
      for (int ni = 0; ni < 4; ni++)
        oacc[md][ni] =
            __builtin_amdgcn_mfma_f32_16x16x32_bf16(va[md], pb[ni], oacc[md][ni], 0, 0, 0);
  }

  // ---- write out: O^T col = i = lane&15, row d = md*16 + kg*4 + r ----
#pragma unroll
  for (int ni = 0; ni < 4; ni++) {
    int i = ni * 16 + il;
    size_t orow = (pbase + (size_t)(i >> 3) * F_W + (i & 7)) * 256 + hh * 32;
#pragma unroll
    for (int md = 0; md < 2; md++) {
      int d0 = md * 16 + kg * 4;
      short4v pk;
#pragma unroll
      for (int r = 0; r < 4; r++) pk[r] = (short)f2bf(oacc[md][ni][r]);
      *(short4v*)(out + orow + d0) = pk;
    }
  }
}

// ---------------- launch ----------------
extern "C" void kernel_launch(void* const* d_in, const int* in_sizes, int n_in,
                              void* d_out, int out_size, void* d_ws, size_t ws_size,
                              hipStream_t stream) {
  const float* x = (const float*)d_in[0];
  const float* y = (const float*)d_in[1];
  const float* Wq = (const float*)d_in[2];
  const float* bq = (const float*)d_in[3];
  const float* Wk = (const float*)d_in[4];
  const float* bk = (const float*)d_in[5];
  const float* Wv = (const float*)d_in[6];
  const float* bv = (const float*)d_in[7];
  const float* gamma = (const float*)d_in[8];
  const float* qkv_w = (const float*)d_in[9];
  const float* q_bias = (const float*)d_in[10];
  const float* v_bias = (const float*)d_in[11];
  const float* logit_scale = (const float*)d_in[12];
  const float* cpb_w1 = (const float*)d_in[13];
  const float* cpb_b1 = (const float*)d_in[14];
  const float* cpb_w2 = (const float*)d_in[15];
  const float* proj_w = (const float*)d_in[16];
  const float* proj_b = (const float*)d_in[17];

  float* ws = (float*)d_ws;
  const size_t NPX = (size_t)F_B * F_HW;  // 131072
  const size_t M1 = NPX * 256;            // 33.55M
  // regions (float offsets):
  size_t f_xt = 0;                 // xt fp32; later: qkvb full bf16 [0, 1.5*M1)
  size_t f_eb = M1;                // ytb/eb bf16
  size_t f_vtb = M1 + M1 / 2;      // xb/vtb bf16
  size_t f_po = 2 * M1;            // po fp32; later: attn_b bf16
  size_t f_ccb = 3 * M1;           // ccb bf16
  size_t f_qkb = 3 * M1 + M1 / 2;  // qkb fp32 (NPX*64)
  size_t f_wts = f_qkb + NPX * 64;
  size_t o_qkwb = f_wts;              // 16384 ushort -> 8192 f
  size_t o_Wvb = o_qkwb + 8192;       // 65536 ushort -> 32768 f
  size_t o_qkvwb = o_Wvb + 32768;     // 196608 ushort -> 98304 f
  size_t o_projwb = o_qkvwb + 98304;  // 65536 ushort -> 32768 f
  size_t o_qkb2 = o_projwb + 32768;   // 64 f
  size_t o_qkvb2 = o_qkb2 + 64;       // 768 f
  size_t o_tbl = o_qkvb2 + 768;       // 1800 f
  size_t o_rsum = o_tbl + 1800;       // NPX f
  size_t o_rpbt = o_rsum + NPX;       // 32768 f
  size_t need = (o_rpbt + 32768) * sizeof(float);
  if (ws_size < need) {
    fprintf(stderr, "kernel_launch: ws too small: %zu < %zu\n", ws_size, need);
    return;
  }
  float* xt = ws + f_xt;
  unsigned short* qkvb = (unsigned short*)(ws + f_xt);  // full qkv bf16, 1.5*M1 f
  unsigned short* ytb = (unsigned short*)(ws + f_eb);
  unsigned short* eb = (unsigned short*)(ws + f_eb);
  unsigned short* xb = (unsigned short*)(ws + f_vtb);
  unsigned short* vtb = (unsigned short*)(ws + f_vtb);
  float* po = ws + f_po;
  unsigned short* attn_b = (unsigned short*)(ws + f_po);
  unsigned short* ccb = (unsigned short*)(ws + f_ccb);
  float* qkb = ws + f_qkb;
  unsigned short* qk_wb = (unsigned short*)(ws + o_qkwb);
  unsigned short* Wvb = (unsigned short*)(ws + o_Wvb);
  unsigned short* qkv_wb = (unsigned short*)(ws + o_qkvwb);
  unsigned short* proj_wb = (unsigned short*)(ws + o_projwb);
  float* qk_b = ws + o_qkb2;
  float* qkv_b = ws + o_qkvb2;
  float* tblS = ws + o_tbl;
  float* rsum = ws + o_rsum;
  float* rpbt = ws + o_rpbt;

  build_aux2<<<dim3(768), dim3(256), 0, stream>>>(Wq, Wk, bq, bk, q_bias, v_bias, Wv, qkv_w,
                                                  proj_w, qk_wb, qk_b, qkv_b, Wvb, qkv_wb,
                                                  proj_wb);
  cpb_table<<<dim3(225), dim3(256), 0, stream>>>(cpb_w1, cpb_b1, cpb_w2, tblS);
  build_rpbt<<<dim3(128), dim3(256), 0, stream>>>(tblS, rpbt);
  // x^T -> xt fp32 + xb bf16 ; y^T -> ytb bf16
  transpose_x<<<dim3(512, 8, 8), dim3(32, 8), 0, stream>>>(x, xt, xb);
  transpose_y<<<dim3(512, 8, 8), dim3(32, 8), 0, stream>>>(y, ytb);
  // q|k projection: (BHW x 256) @ (64 x 256)^T -> fp32
  gemm_mfma<64, 0><<<dim3(1, 1024), dim3(256), 0, stream>>>(xb, qk_wb, qk_b, qkb, (int)NPX,
                                                            64);
  // v projection -> bf16 vtb
  gemm_mfma<128, 2><<<dim3(2, 1024), dim3(256), 0, stream>>>(ytb, Wvb, bv, vtb, (int)NPX, 256);
  // criss-cross attention (GEMM-structured, bf16 e)
  cc_logits<0><<<dim3(128, 8), dim3(256), 0, stream>>>(qkb, eb);
  cc_logits<1><<<dim3(128, 8), dim3(256), 0, stream>>>(qkb, eb);
  cc_sums<<<dim3(32768), dim3(256), 0, stream>>>(eb, rsum);
  cc_pv_mfma<0><<<dim3(128, 8), dim3(256), 0, stream>>>(eb, vtb, rsum, gamma, xt, po, ccb);
  cc_pv_mfma<1><<<dim3(128, 8), dim3(256), 0, stream>>>(eb, vtb, rsum, gamma, xt, po, ccb);
  // window qkv projection (full, bf16) + window attention (MFMA)
  gemm_mfma<128, 2><<<dim3(6, 1024), dim3(256), 0, stream>>>(ccb, qkv_wb, qkv_b, qkvb,
                                                             (int)NPX, 768);
  win_attn_mfma<<<dim3(2048, 2), dim3(256), 0, stream>>>(qkvb, logit_scale, rpbt, attn_b);
  // output projection with transposed (B,C,H,W) write
  gemm_mfma<128, 1><<<dim3(2, 1024), dim3(256), 0, stream>>>(attn_b, proj_wb, proj_b, d_out,
                                                             (int)NPX, 256);
}

// Round 7
// 618.826 us; speedup vs baseline: 6.9719x; 1.1323x over previous
//
#include <hip/hip_runtime.h>
#include <cstdio>
#include <cstddef>
#include <cstdint>

#define F_B 8
#define F_C 256
#define F_H 128
#define F_W 128
#define F_HW 16384

typedef __attribute__((ext_vector_type(8))) short short8;   // bf16x8 MFMA operand
typedef __attribute__((ext_vector_type(4))) short short4v;  // bf16x4
typedef __attribute__((ext_vector_type(4))) float float4v;  // MFMA accumulator

__device__ __forceinline__ unsigned short f2bf(float f) {
  union {
    float f;
    uint32_t u;
  } v;
  v.f = f;
  return (unsigned short)((v.u + 0x7fffu + ((v.u >> 16) & 1u)) >> 16);
}

__device__ __forceinline__ float bf2f(unsigned short u) {
  union {
    uint32_t u;
    float f;
  } v;
  v.u = ((uint32_t)u) << 16;
  return v.f;
}

__device__ __forceinline__ void async_copy16(const unsigned short* g, unsigned short* l) {
  __builtin_amdgcn_global_load_lds((const __attribute__((address_space(1))) void*)g,
                                   (__attribute__((address_space(3))) void*)l, 16, 0, 0);
}

// ---------------- aux: weight bf16 conversion + bias concat ----------------
__global__ void build_aux2(const float* __restrict__ Wq, const float* __restrict__ Wk,
                           const float* __restrict__ bq, const float* __restrict__ bk,
                           const float* __restrict__ q_bias, const float* __restrict__ v_bias,
                           const float* __restrict__ Wv, const float* __restrict__ qkv_w,
                           const float* __restrict__ proj_w, unsigned short* __restrict__ qk_wb,
                           float* __restrict__ qk_b, float* __restrict__ qkv_b,
                           unsigned short* __restrict__ Wvb, unsigned short* __restrict__ qkv_wb,
                           unsigned short* __restrict__ proj_wb) {
  int t = blockIdx.x * 256 + threadIdx.x;  // 768 blocks -> 196608 threads
  if (t < 8192) {
    qk_wb[t] = f2bf(Wq[t]);
    qk_wb[8192 + t] = f2bf(Wk[t]);
  }
  if (t < 65536) {
    Wvb[t] = f2bf(Wv[t]);
    proj_wb[t] = f2bf(proj_w[t]);
  }
  if (t < 196608) qkv_wb[t] = f2bf(qkv_w[t]);
  if (t < 32) {
    qk_b[t] = bq[t];
    qk_b[32 + t] = bk[t];
  }
  if (t < 256) {
    qkv_b[t] = q_bias[t];
    qkv_b[256 + t] = 0.0f;
    qkv_b[512 + t] = v_bias[t];
  }
}

// ---------------- CPB MLP table: tblS[225][8] = 16*sigmoid(mlp(coords)) -----
__device__ __forceinline__ float cpb_coord(int a) {
  float v = (float)(a - 7) * (8.0f / 7.0f);
  float lg = log2f(fabsf(v) + 1.0f) * (1.0f / 3.0f);  // /log2(8)
  return (v < 0.0f) ? -lg : lg;
}

__global__ void cpb_table(const float* __restrict__ w1, const float* __restrict__ b1,
                          const float* __restrict__ w2, float* __restrict__ tblS) {
  int e = blockIdx.x;  // 0..224
  int yi = e / 15, xi = e % 15;
  float ry = cpb_coord(yi), rx = cpb_coord(xi);
  __shared__ float hid[512];
  int t = threadIdx.x;  // 256
  for (int j = t; j < 512; j += 256) {
    float hv = w1[j * 2] * ry + w1[j * 2 + 1] * rx + b1[j];
    hid[j] = fmaxf(hv, 0.0f);
  }
  __syncthreads();
  if (t < 8) {
    float s = 0.0f;
    for (int j = 0; j < 512; j++) s += hid[j] * w2[t * 512 + j];
    tblS[e * 8 + t] = 16.0f / (1.0f + __expf(-s));
  }
}

// ---------------- rpbt[h][i][j] = tblS[e(i,j)*8+h]  (window-independent) ----
__global__ void build_rpbt(const float* __restrict__ tblS, float* __restrict__ rpbt) {
  int t = blockIdx.x * 256 + threadIdx.x;  // < 32768
  int h = t >> 12, i = (t >> 6) & 63, j = t & 63;
  int e = ((i >> 3) - (j >> 3) + 7) * 15 + ((i & 7) - (j & 7) + 7);
  rpbt[t] = tblS[e * 8 + h];
}

// ---------------- transpose (B,C,HW) -> (B,HW,C) bf16 ----------------
__global__ void transpose_bf(const float* __restrict__ in, unsigned short* __restrict__ outb) {
  __shared__ float tile[32][33];
  int b = blockIdx.z;
  int p0 = blockIdx.x * 32;
  int c0 = blockIdx.y * 32;
  const float* src = in + (size_t)b * F_C * F_HW;
  int tx = threadIdx.x, ty = threadIdx.y;  // 32 x 8
#pragma unroll
  for (int i = 0; i < 4; i++) {
    tile[ty + i * 8][tx] = src[(size_t)(c0 + ty + i * 8) * F_HW + p0 + tx];
  }
  __syncthreads();
#pragma unroll
  for (int i = 0; i < 4; i++) {
    size_t idx = (size_t)b * F_HW * F_C + (size_t)(p0 + ty + i * 8) * F_C + c0 + tx;
    outb[idx] = f2bf(tile[tx][ty + i * 8]);
  }
}

// ---------------- bf16 MFMA GEMM: C[M,N] = A[M,256] @ W[N,256]^T + bias ----
// 1-D grid with XCD-chunked swizzle (gridDim.x % 8 == 0, x-fast within chunk).
// OUT 0: fp32 row-major. OUT 1: fp32 out[((row>>14)*N+col)*16384+(row&16383)].
// OUT 2: bf16 row-major.
template <int BN, int OUT>
__global__ __launch_bounds__(256) void gemm_mfma(const unsigned short* __restrict__ A,
                                                 const unsigned short* __restrict__ Wt,
                                                 const float* __restrict__ bias, void* Cmat,
                                                 int M, int N, int gx) {
  constexpr int WN = BN / 2;
  constexpr int NREP = WN / 16;
  __shared__ __align__(16) unsigned short As[128 * 32];
  __shared__ __align__(16) unsigned short Bs[BN * 32];
  int nwg = gridDim.x;
  int id = blockIdx.x;
  int cpx = nwg >> 3;
  int swz = (id & 7) * cpx + (id >> 3);
  int by = swz / gx;
  int bx = swz - by * gx;
  int m0 = by * 128;
  int n0 = bx * BN;
  int t = threadIdx.x;
  int wid = t >> 6, lane = t & 63;
  int wr = wid >> 1, wc = wid & 1;

  float4v acc[4][NREP] = {};

  for (int k0 = 0; k0 < 256; k0 += 32) {
    __syncthreads();
#pragma unroll
    for (int j = 0; j < 2; j++) {
      int r = wid * 32 + j * 16 + (lane >> 2);
      int kg = (lane & 3) ^ (r & 3);  // inverse swizzle on global source
      const unsigned short* gp = A + (size_t)(m0 + r) * 256 + k0 + kg * 8;
      async_copy16(gp, As + (wid * 32 + j * 16) * 32);
    }
#pragma unroll
    for (int j = 0; j < BN / 64; j++) {
      int r = wid * (BN / 4) + j * 16 + (lane >> 2);
      int kg = (lane & 3) ^ (r & 3);
      const unsigned short* gp = Wt + (size_t)(n0 + r) * 256 + k0 + kg * 8;
      async_copy16(gp, Bs + (wid * (BN / 4) + j * 16) * 32);
    }
    __syncthreads();
    short8 af[4];
#pragma unroll
    for (int mi = 0; mi < 4; mi++) {
      int row = wr * 64 + mi * 16 + (lane & 15);
      int kg = (lane >> 4) ^ (row & 3);
      af[mi] = *(const short8*)(As + row * 32 + kg * 8);
    }
    short8 bfr[NREP];
#pragma unroll
    for (int ni = 0; ni < NREP; ni++) {
      int col = wc * WN + ni * 16 + (lane & 15);
      int kg = (lane >> 4) ^ (col & 3);
      bfr[ni] = *(const short8*)(Bs + col * 32 + kg * 8);
    }
#pragma unroll
    for (int mi = 0; mi < 4; mi++)
#pragma unroll
      for (int ni = 0; ni < NREP; ni++)
        acc[mi][ni] =
            __builtin_amdgcn_mfma_f32_16x16x32_bf16(af[mi], bfr[ni], acc[mi][ni], 0, 0, 0);
  }
#pragma unroll
  for (int ni = 0; ni < NREP; ni++) {
    int col = n0 + wc * WN + ni * 16 + (lane & 15);
    float bn = bias[col];
#pragma unroll
    for (int mi = 0; mi < 4; mi++) {
      int row0 = m0 + wr * 64 + mi * 16 + (lane >> 4) * 4;
#pragma unroll
      for (int r = 0; r < 4; r++) {
        float v = acc[mi][ni][r] + bn;
        int row = row0 + r;
        if (OUT == 0) {
          ((float*)Cmat)[(size_t)row * N + col] = v;
        } else if (OUT == 1) {
          int bb = row >> 14, p = row & 16383;
          ((float*)Cmat)[((size_t)bb * N + col) * F_HW + p] = v;
        } else {
          ((unsigned short*)Cmat)[(size_t)row * N + col] = f2bf(v);
        }
      }
    }
  }
}

// ---------------- criss-cross logits (bf16 exp output + partial row sum) ----
// MODE 0 (H/column): block (w=x, b); E[h,g] = q(h,x)·k(g,x); e[pix(h,x)][g], diag->0
// MODE 1 (W/row):    block (h=x, b); E[w,v] = q(x,w)·k(x,v); e[pix(x,w)][128+v]
// sums[pix] = sum over this mode's 128 exps.
template <int MODE>
__global__ __launch_bounds__(256) void cc_logits(const float* __restrict__ qk,
                                                 unsigned short* __restrict__ e,
                                                 float* __restrict__ sums) {
  int x = blockIdx.x;
  int b = blockIdx.y;
  size_t base = (size_t)b * F_HW;
  __shared__ float kt[32][132];  // kt[c][g]
  int t = threadIdx.x;
  {
    int gk = t >> 1, c0 = (t & 1) * 16;
    size_t krow = (MODE == 0) ? ((size_t)gk * F_W + x) : ((size_t)x * F_W + gk);
    const float4* src = (const float4*)(qk + (base + krow) * 64 + 32 + c0);
#pragma unroll
    for (int q4 = 0; q4 < 4; q4++) {
      float4 v = src[q4];
      kt[c0 + q4 * 4 + 0][gk] = v.x;
      kt[c0 + q4 * 4 + 1][gk] = v.y;
      kt[c0 + q4 * 4 + 2][gk] = v.z;
      kt[c0 + q4 * 4 + 3][gk] = v.w;
    }
  }
  __syncthreads();
  int i = t >> 1, g0 = (t & 1) * 64;
  size_t qrow = (MODE == 0) ? ((size_t)i * F_W + x) : ((size_t)x * F_W + i);
  const float4* qp = (const float4*)(qk + (base + qrow) * 64);
  float qreg[32];
#pragma unroll
  for (int q4 = 0; q4 < 8; q4++) {
    float4 v = qp[q4];
    qreg[q4 * 4 + 0] = v.x;
    qreg[q4 * 4 + 1] = v.y;
    qreg[q4 * 4 + 2] = v.z;
    qreg[q4 * 4 + 3] = v.w;
  }
  float acc[64];
#pragma unroll
  for (int g = 0; g < 64; g++) acc[g] = 0.0f;
  for (int c = 0; c < 32; c++) {
    float qv = qreg[c];
#pragma unroll
    for (int g = 0; g < 64; g++) acc[g] += qv * kt[c][g0 + g];
  }
  if (MODE == 0) {
    int d = i - g0;
    if (d >= 0 && d < 64) acc[d] = -1e9f;  // diag mask -> exp = 0
  }
  unsigned short* ep = e + (base + qrow) * 256 + MODE * 128 + g0;
  float s = 0.0f;
#pragma unroll
  for (int g = 0; g < 64; g += 8) {
    short8 pk;
#pragma unroll
    for (int j = 0; j < 8; j++) {
      float ev = __expf(acc[g + j]);
      s += ev;
      pk[j] = (short)f2bf(ev);
    }
    *(short8*)(ep + g) = pk;
  }
  s += __shfl_xor(s, 1);  // pair (t, t^1) share the same row i
  if ((t & 1) == 0) sums[base + qrow] = s;
}

// ---------------- criss-cross PV, bf16 MFMA ----------------
// O[i][c] = sum_k Anorm[i][k] * V[k][c] per (x,b) block; 128x256x128.
// MODE 0: i=h (col x fixed), k=g, pix(i)=i*128+x  -> writes pob = bf16 raw oH
// MODE 1: i=w (row x fixed), k=v, pix(i)=x*128+i  -> ccb = bf16(gm*(po+oW)+x)
template <int MODE>
__global__ __launch_bounds__(256) void cc_pv_mfma(const unsigned short* __restrict__ eb,
                                                  const unsigned short* __restrict__ vtb,
                                                  const float* __restrict__ sumH,
                                                  const float* __restrict__ sumW,
                                                  const float* __restrict__ gamma,
                                                  const unsigned short* __restrict__ xb,
                                                  unsigned short* __restrict__ pob,
                                                  unsigned short* __restrict__ ccb) {
  int x = blockIdx.x, b = blockIdx.y;
  size_t base = (size_t)b * F_HW;
  __shared__ __align__(16) unsigned short As[128 * 128];  // [i][k], swizzled, 32 KB
  __shared__ __align__(16) unsigned short Vs[256 * 64];   // [c][k-chunk], swizzled, 32 KB
  int t = threadIdx.x;
  int wid = t >> 6, lane = t & 63;
  int wr = wid >> 1, wc = wid & 1;
  // ---- stage A = normalized e (bf16) ----
  {
    int i = t >> 1, half = t & 1;
    size_t pix = (MODE == 0) ? ((size_t)i * F_W + x) : ((size_t)x * F_W + i);
    float rv = 1.0f / (sumH[base + pix] + sumW[base + pix]);
    const unsigned short* ep = eb + (base + pix) * 256 + MODE * 128 + half * 64;
    int g = ((i >> 3) & 7) ^ (i & 7);
#pragma unroll
    for (int s = 0; s < 8; s++) {
      short8 vin = *(const short8*)(ep + s * 8);
      short8 vo;
#pragma unroll
      for (int j = 0; j < 8; j++) vo[j] = (short)f2bf(bf2f((unsigned short)vin[j]) * rv);
      int slot = (half * 8 + s) ^ g;  // g is 3-bit: half bit preserved
      *(short8*)(As + i * 128 + slot * 8) = vo;
    }
  }
  float4v acc[4][8] = {};
#pragma unroll
  for (int kc = 0; kc < 2; kc++) {
    __syncthreads();
    // ---- stage Vs[c][k] for k-chunk kc: in-register 8x8 transpose ----
    {
      int ko = t >> 5, cj = t & 31;
      short8 rowv[8];
#pragma unroll
      for (int r = 0; r < 8; r++) {
        int kk = kc * 64 + ko * 8 + r;
        size_t pixk = (MODE == 0) ? ((size_t)kk * F_W + x) : ((size_t)x * F_W + kk);
        rowv[r] = *(const short8*)(vtb + (base + pixk) * 256 + cj * 8);
      }
#pragma unroll
      for (int j = 0; j < 8; j++) {
        short8 col;
#pragma unroll
        for (int r = 0; r < 8; r++) col[r] = rowv[r][j];
        int c = cj * 8 + j;
        int slot = ko ^ ((c >> 3) & 7) ^ (c & 7);
        *(short8*)(Vs + c * 64 + slot * 8) = col;
      }
    }
    __syncthreads();
#pragma unroll
    for (int ksub = 0; ksub < 2; ksub++) {
      short8 af[4];
#pragma unroll
      for (int mi = 0; mi < 4; mi++) {
        int i = wr * 64 + mi * 16 + (lane & 15);
        int slot = (kc * 8 + ksub * 4 + (lane >> 4)) ^ ((i >> 3) & 7) ^ (i & 7);
        af[mi] = *(const short8*)(As + i * 128 + slot * 8);
      }
      short8 bfv[8];
#pragma unroll
      for (int ni = 0; ni < 8; ni++) {
        int c = wc * 128 + ni * 16 + (lane & 15);
        int slot = (ksub * 4 + (lane >> 4)) ^ ((c >> 3) & 7) ^ (c & 7);
        bfv[ni] = *(const short8*)(Vs + c * 64 + slot * 8);
      }
#pragma unroll
      for (int mi = 0; mi < 4; mi++)
#pragma unroll
        for (int ni = 0; ni < 8; ni++)
          acc[mi][ni] =
              __builtin_amdgcn_mfma_f32_16x16x32_bf16(af[mi], bfv[ni], acc[mi][ni], 0, 0, 0);
    }
  }
  // ---- epilogue ----
  float gm = gamma[0];
#pragma unroll
  for (int mi = 0; mi < 4; mi++) {
#pragma unroll
    for (int ni = 0; ni < 8; ni++) {
#pragma unroll
      for (int r = 0; r < 4; r++) {
        int i = wr * 64 + mi * 16 + (lane >> 4) * 4 + r;
        int c = wc * 128 + ni * 16 + (lane & 15);
        size_t pix = (MODE == 0) ? ((size_t)i * F_W + x) : ((size_t)x * F_W + i);
        size_t idx = (base + pix) * 256 + c;
        if (MODE == 0) {
          pob[idx] = f2bf(acc[mi][ni][r]);
        } else {
          float v = gm * (bf2f(pob[idx]) + acc[mi][ni][r]) + bf2f(xb[idx]);
          ccb[idx] = f2bf(v);
        }
      }
    }
  }
}

// ---------------- window attention, MFMA: 1 wave per (window, head) --------
// qkv: [NPX][768] bf16 (q|k|v, head-major 32). out: [NPX][256] bf16.
// rpbt: [8][64][64] fp32 = 16*sigmoid(cpb) per (head, i, j).
__global__ __launch_bounds__(256) void win_attn_mfma(const unsigned short* __restrict__ qkv,
                                                     const float* __restrict__ logit_scale,
                                                     const float* __restrict__ rpbt,
                                                     unsigned short* __restrict__ out) {
  __shared__ __align__(16) unsigned short Pl[4][4096];  // per-wave P[i][j] bf16, swizzled
  __shared__ __align__(16) unsigned short Vt[4][2048];  // per-wave V^T[d][j] bf16, swizzled
  int win = blockIdx.x;
  int wid = threadIdx.x >> 6, lane = threadIdx.x & 63;
  int hh = blockIdx.y * 4 + wid;
  int b = win >> 8, wy = (win >> 4) & 15, wx = win & 15;
  size_t pbase = (size_t)b * F_HW + (size_t)(wy * 8) * F_W + wx * 8;
  int il = lane & 15, kg = lane >> 4;

  // ---- load + cosine-normalize Q (B-frags) and K (A-frags) ----
  short8 qb[4], ka[4];
#pragma unroll
  for (int ni = 0; ni < 4; ni++) {
    int i = ni * 16 + il;
    size_t row = (pbase + (size_t)(i >> 3) * F_W + (i & 7)) * 768 + hh * 32 + kg * 8;
    short8 qv = *(const short8*)(qkv + row);
    short8 kv = *(const short8*)(qkv + row + 256);
    float qss = 0.0f, kss = 0.0f;
#pragma unroll
    for (int j = 0; j < 8; j++) {
      float qf = bf2f((unsigned short)qv[j]);
      float kf = bf2f((unsigned short)kv[j]);
      qss += qf * qf;
      kss += kf * kf;
    }
    qss += __shfl_xor(qss, 16);
    qss += __shfl_xor(qss, 32);
    kss += __shfl_xor(kss, 16);
    kss += __shfl_xor(kss, 32);
    float qinv = 1.0f / fmaxf(sqrtf(qss), 1e-12f);
    float kinv = 1.0f / fmaxf(sqrtf(kss), 1e-12f);
#pragma unroll
    for (int j = 0; j < 8; j++) {
      qb[ni][j] = (short)f2bf(bf2f((unsigned short)qv[j]) * qinv);
      ka[ni][j] = (short)f2bf(bf2f((unsigned short)kv[j]) * kinv);
    }
  }

  // ---- stage V^T[d][j] (lanes 0..31, in-register 8x8 transpose) ----
  if (lane < 32) {
    int jb = lane >> 2, db = lane & 3;
    short8 rows[8];
#pragma unroll
    for (int r = 0; r < 8; r++) {
      rows[r] =
          *(const short8*)(qkv + (pbase + (size_t)jb * F_W + r) * 768 + hh * 32 + 512 + db * 8);
    }
#pragma unroll
    for (int c = 0; c < 8; c++) {
      int d = db * 8 + c;
      short8 col;
#pragma unroll
      for (int r = 0; r < 8; r++) col[r] = rows[r][c];
      *(short8*)(Vt[wid] + d * 64 + ((jb ^ (d & 7)) * 8)) = col;
    }
  }

  // ---- S^T = K @ Q^T (D[j][i]) ----
  float4v sacc[4][4] = {};
#pragma unroll
  for (int mj = 0; mj < 4; mj++)
#pragma unroll
    for (int ni = 0; ni < 4; ni++)
      sacc[mj][ni] = __builtin_amdgcn_mfma_f32_16x16x32_bf16(ka[mj], qb[ni], sacc[mj][ni], 0, 0, 0);

  float scale = __expf(fminf(logit_scale[hh], 4.605170185988091f));  // ln(100)

  // ---- softmax over j (per col i), write P[i][j] bf16 to LDS ----
#pragma unroll
  for (int ni = 0; ni < 4; ni++) {
    int i = ni * 16 + il;
    const float* rp = rpbt + ((size_t)hh * 64 + i) * 64;
    float sv[16];
    float mx = -1e30f;
#pragma unroll
    for (int mj = 0; mj < 4; mj++) {
      float4 rb = *(const float4*)(rp + mj * 16 + kg * 4);
      float rbs[4] = {rb.x, rb.y, rb.z, rb.w};
#pragma unroll
      for (int r = 0; r < 4; r++) {
        float v = sacc[mj][ni][r] * scale + rbs[r];
        sv[mj * 4 + r] = v;
        mx = fmaxf(mx, v);
      }
    }
    mx = fmaxf(mx, __shfl_xor(mx, 16));
    mx = fmaxf(mx, __shfl_xor(mx, 32));
    float sm = 0.0f;
#pragma unroll
    for (int u = 0; u < 16; u++) {
      sv[u] = __expf(sv[u] - mx);
      sm += sv[u];
    }
    sm += __shfl_xor(sm, 16);
    sm += __shfl_xor(sm, 32);
    float inv = 1.0f / sm;
#pragma unroll
    for (int mj = 0; mj < 4; mj++) {
      int j0 = mj * 16 + kg * 4;
      short4v pk;
#pragma unroll
      for (int r = 0; r < 4; r++) pk[r] = (short)f2bf(sv[mj * 4 + r] * inv);
      int byteoff = i * 128 + (((j0 >> 3) ^ (i & 7)) * 16) + (j0 & 7) * 2;
      *(short4v*)((char*)Pl[wid] + byteoff) = pk;
    }
  }
  __syncthreads();

  // ---- O^T = V^T @ P^T: A = V^T[d][j], B[k=j][n=i] = P[i][j] ----
  float4v oacc[2][4] = {};
#pragma unroll
  for (int kc = 0; kc < 2; kc++) {
    short8 va[2];
#pragma unroll
    for (int md = 0; md < 2; md++) {
      int d = md * 16 + il;
      va[md] = *(const short8*)((char*)Vt[wid] + d * 128 + (((kc * 4 + kg) ^ (d & 7)) * 16));
    }
    short8 pb[4];
#pragma unroll
    for (int ni = 0; ni < 4; ni++) {
      int i = ni * 16 + il;
      pb[ni] = *(const short8*)((char*)Pl[wid] + i * 128 + (((kc * 4 + kg) ^ (i & 7)) * 16));
    }
#pragma unroll
    for (int md = 0; md < 2; md++)
#pragma unroll
      for (int ni = 0; ni < 4; ni++)
        oacc[md][ni] =
            __builtin_amdgcn_mfma_f32_16x16x32_bf16(va[md], pb[ni], oacc[md][ni], 0, 0, 0);
  }

  // ---- write out: O^T col = i = lane&15, row d = md*16 + kg*4 + r ----
#pragma unroll
  for (int ni = 0; ni < 4; ni++) {
    int i = ni * 16 + il;
    size_t orow = (pbase + (size_t)(i >> 3) * F_W + (i & 7)) * 256 + hh * 32;
#pragma unroll
    for (int md = 0; md < 2; md++) {
      int d0 = md * 16 + kg * 4;
      short4v pk;
#pragma unroll
      for (int r = 0; r < 4; r++) pk[r] = (short)f2bf(oacc[md][ni][r]);
      *(short4v*)(out + orow + d0) = pk;
    }
  }
}

// ---------------- launch ----------------
extern "C" void kernel_launch(void* const* d_in, const int* in_sizes, int n_in,
                              void* d_out, int out_size, void* d_ws, size_t ws_size,
                              hipStream_t stream) {
  const float* x = (const float*)d_in[0];
  const float* y = (const float*)d_in[1];
  const float* Wq = (const float*)d_in[2];
  const float* bq = (const float*)d_in[3];
  const float* Wk = (const float*)d_in[4];
  const float* bk = (const float*)d_in[5];
  const float* Wv = (const float*)d_in[6];
  const float* bv = (const float*)d_in[7];
  const float* gamma = (const float*)d_in[8];
  const float* qkv_w = (const float*)d_in[9];
  const float* q_bias = (const float*)d_in[10];
  const float* v_bias = (const float*)d_in[11];
  const float* logit_scale = (const float*)d_in[12];
  const float* cpb_w1 = (const float*)d_in[13];
  const float* cpb_b1 = (const float*)d_in[14];
  const float* cpb_w2 = (const float*)d_in[15];
  const float* proj_w = (const float*)d_in[16];
  const float* proj_b = (const float*)d_in[17];

  float* ws = (float*)d_ws;
  const size_t NPX = (size_t)F_B * F_HW;  // 131072
  const size_t M1 = NPX * 256;            // 33.55M floats (= bf16 plane is M1/2 floats)
  // regions (float offsets). bf16 planes are M1/2 floats each:
  size_t f_xb = 0;                 // xb bf16 [0, M1/2)
  size_t f_ytb = M1 / 2;           // ytb bf16; eb bf16 overlays after v-GEMM
  size_t f_vtb = M1;               // vtb bf16
  size_t f_pob = M1 + M1 / 2;      // pob bf16; attn_b bf16 overlays after pv
  size_t f_ccb = 2 * M1;           // ccb bf16
  size_t f_qkb = 2 * M1 + M1 / 2;  // qkb fp32 (NPX*64)
  // qkvb bf16 (1.5*M1 floats) overlays [0, 1.5*M1) after pv<1> (xb/eb/vtb dead)
  size_t f_wts = f_qkb + NPX * 64;
  size_t o_qkwb = f_wts;              // 16384 ushort -> 8192 f
  size_t o_Wvb = o_qkwb + 8192;       // 65536 ushort -> 32768 f
  size_t o_qkvwb = o_Wvb + 32768;     // 196608 ushort -> 98304 f
  size_t o_projwb = o_qkvwb + 98304;  // 65536 ushort -> 32768 f
  size_t o_qkb2 = o_projwb + 32768;   // 64 f
  size_t o_qkvb2 = o_qkb2 + 64;       // 768 f
  size_t o_tbl = o_qkvb2 + 768;       // 1800 f
  size_t o_sumH = o_tbl + 1800;       // NPX f
  size_t o_sumW = o_sumH + NPX;       // NPX f
  size_t o_rpbt = o_sumW + NPX;       // 32768 f
  size_t need = (o_rpbt + 32768) * sizeof(float);
  if (ws_size < need) {
    fprintf(stderr, "kernel_launch: ws too small: %zu < %zu\n", ws_size, need);
    return;
  }
  unsigned short* xb = (unsigned short*)(ws + f_xb);
  unsigned short* qkvb = (unsigned short*)(ws + f_xb);  // overlays [0, 1.5*M1)
  unsigned short* ytb = (unsigned short*)(ws + f_ytb);
  unsigned short* eb = (unsigned short*)(ws + f_ytb);
  unsigned short* vtb = (unsigned short*)(ws + f_vtb);
  unsigned short* pob = (unsigned short*)(ws + f_pob);
  unsigned short* attn_b = (unsigned short*)(ws + f_pob);
  unsigned short* ccb = (unsigned short*)(ws + f_ccb);
  float* qkb = ws + f_qkb;
  unsigned short* qk_wb = (unsigned short*)(ws + o_qkwb);
  unsigned short* Wvb = (unsigned short*)(ws + o_Wvb);
  unsigned short* qkv_wb = (unsigned short*)(ws + o_qkvwb);
  unsigned short* proj_wb = (unsigned short*)(ws + o_projwb);
  float* qk_b = ws + o_qkb2;
  float* qkv_b = ws + o_qkvb2;
  float* tblS = ws + o_tbl;
  float* sumH = ws + o_sumH;
  float* sumW = ws + o_sumW;
  float* rpbt = ws + o_rpbt;

  build_aux2<<<dim3(768), dim3(256), 0, stream>>>(Wq, Wk, bq, bk, q_bias, v_bias, Wv, qkv_w,
                                                  proj_w, qk_wb, qk_b, qkv_b, Wvb, qkv_wb,
                                                  proj_wb);
  cpb_table<<<dim3(225), dim3(256), 0, stream>>>(cpb_w1, cpb_b1, cpb_w2, tblS);
  build_rpbt<<<dim3(128), dim3(256), 0, stream>>>(tblS, rpbt);
  // x^T -> xb bf16 ; y^T -> ytb bf16
  transpose_bf<<<dim3(512, 8, 8), dim3(32, 8), 0, stream>>>(x, xb);
  transpose_bf<<<dim3(512, 8, 8), dim3(32, 8), 0, stream>>>(y, ytb);
  // q|k projection: (BHW x 256) @ (64 x 256)^T -> fp32
  gemm_mfma<64, 0><<<dim3(1024), dim3(256), 0, stream>>>(xb, qk_wb, qk_b, qkb, (int)NPX, 64,
                                                         1);
  // v projection -> bf16 vtb
  gemm_mfma<128, 2><<<dim3(2048), dim3(256), 0, stream>>>(ytb, Wvb, bv, vtb, (int)NPX, 256, 2);
  // criss-cross attention (GEMM-structured, bf16 e, fused partial sums)
  cc_logits<0><<<dim3(128, 8), dim3(256), 0, stream>>>(qkb, eb, sumH);
  cc_logits<1><<<dim3(128, 8), dim3(256), 0, stream>>>(qkb, eb, sumW);
  cc_pv_mfma<0><<<dim3(128, 8), dim3(256), 0, stream>>>(eb, vtb, sumH, sumW, gamma, xb, pob,
                                                        ccb);
  cc_pv_mfma<1><<<dim3(128, 8), dim3(256), 0, stream>>>(eb, vtb, sumH, sumW, gamma, xb, pob,
                                                        ccb);
  // window qkv projection (full, bf16) + window attention (MFMA)
  gemm_mfma<128, 2><<<dim3(6144), dim3(256), 0, stream>>>(ccb, qkv_wb, qkv_b, qkvb, (int)NPX,
                                                          768, 6);
  win_attn_mfma<<<dim3(2048, 2), dim3(256), 0, stream>>>(qkvb, logit_scale, rpbt, attn_b);
  // output projection with transposed (B,C,H,W) write
  gemm_mfma<128, 1><<<dim3(2048), dim3(256), 0, stream>>>(attn_b, proj_wb, proj_b, d_out,
                                                          (int)NPX, 256, 2);
}